// Round 1
// baseline (1768.812 us; speedup 1.0000x reference)
//
#include <hip/hip_runtime.h>
#include <cstddef>

#define EDIM 512
#define KDIM 768
#define NB 64
#define NV 196
#define NT 64
#define MROWS_V (NB * NV) /* 12544 */
#define MROWS_T (NB * NT) /* 4096  */

// ---------------- transpose W [768x512] -> Wt [512x768] ----------------
__global__ void k_transpose(const float* __restrict__ W0, const float* __restrict__ W1,
                            float* __restrict__ T0, float* __restrict__ T1) {
  __shared__ float tile[32][33];
  const float* W = blockIdx.z ? W1 : W0;
  float*       T = blockIdx.z ? T1 : T0;
  int k0 = blockIdx.x * 32;
  int n0 = blockIdx.y * 32;
  int tx = threadIdx.x, ty = threadIdx.y;
  for (int i = ty; i < 32; i += 8)
    tile[i][tx] = W[(size_t)(k0 + i) * EDIM + n0 + tx];
  __syncthreads();
  for (int i = ty; i < 32; i += 8)
    T[(size_t)(n0 + i) * KDIM + k0 + tx] = tile[tx][i];
}

// ---------- projection GEMM: C[r,n] = sum_k X[r,k]*Wt[n,k] + bias[n] ----------
// tile 128 rows x 64 cols, K-chunk 64, 256 threads, 8x4 micro-tile
__global__ __launch_bounds__(256, 2) void k_proj(const float* __restrict__ X,
                                                 const float* __restrict__ Wt,
                                                 const float* __restrict__ bias,
                                                 float* __restrict__ C) {
  __shared__ float Xs[128 * 68];
  __shared__ float Ws[64 * 68];
  int n0 = blockIdx.x * 64;
  int r0 = blockIdx.y * 128;
  int tid = threadIdx.x;
  int ty = tid >> 4, tx = tid & 15;
  float acc[8][4] = {};
  for (int k0 = 0; k0 < KDIM; k0 += 64) {
    for (int u = tid; u < 128 * 16; u += 256) {
      int r = u >> 4, kq = (u & 15) << 2;
      *(float4*)(Xs + r * 68 + kq) =
          *(const float4*)(X + (size_t)(r0 + r) * KDIM + k0 + kq);
    }
    for (int u = tid; u < 64 * 16; u += 256) {
      int n = u >> 4, kq = (u & 15) << 2;
      *(float4*)(Ws + n * 68 + kq) =
          *(const float4*)(Wt + (size_t)(n0 + n) * KDIM + k0 + kq);
    }
    __syncthreads();
    for (int k = 0; k < 64; k += 4) {
      float4 xa[8], wb[4];
#pragma unroll
      for (int i = 0; i < 8; i++) xa[i] = *(const float4*)(Xs + (ty + 16 * i) * 68 + k);
#pragma unroll
      for (int j = 0; j < 4; j++) wb[j] = *(const float4*)(Ws + (tx + 16 * j) * 68 + k);
#pragma unroll
      for (int i = 0; i < 8; i++)
#pragma unroll
        for (int j = 0; j < 4; j++)
          acc[i][j] += xa[i].x * wb[j].x + xa[i].y * wb[j].y +
                       xa[i].z * wb[j].z + xa[i].w * wb[j].w;
    }
    __syncthreads();
  }
#pragma unroll
  for (int j = 0; j < 4; j++) {
    int n = n0 + tx + 16 * j;
    float bb = bias[n];
#pragma unroll
    for (int i = 0; i < 8; i++)
      C[(size_t)(r0 + ty + 16 * i) * EDIM + n] = acc[i][j] + bb;
  }
}

// ------- per-row: fc scalar (pre-norm) + l2 normalize in place; 1 wave/row -------
__global__ void k_normfc(float* __restrict__ M, const float* __restrict__ fcw,
                         const float* __restrict__ fcb, float* __restrict__ wout,
                         int nrows) {
  int row = blockIdx.x * 4 + (threadIdx.x >> 6);
  int lane = threadIdx.x & 63;
  if (row >= nrows) return;
  float* p = M + (size_t)row * EDIM;
  float4 a0 = *(float4*)(p + lane * 8);
  float4 a1 = *(float4*)(p + lane * 8 + 4);
  float4 w0 = *(const float4*)(fcw + lane * 8);
  float4 w1 = *(const float4*)(fcw + lane * 8 + 4);
  float dot = a0.x * w0.x + a0.y * w0.y + a0.z * w0.z + a0.w * w0.w +
              a1.x * w1.x + a1.y * w1.y + a1.z * w1.z + a1.w * w1.w;
  float ss = a0.x * a0.x + a0.y * a0.y + a0.z * a0.z + a0.w * a0.w +
             a1.x * a1.x + a1.y * a1.y + a1.z * a1.z + a1.w * a1.w;
  for (int s = 1; s < 64; s <<= 1) {
    dot += __shfl_xor(dot, s);
    ss += __shfl_xor(ss, s);
  }
  float inv = 1.0f / fmaxf(sqrtf(ss), 1e-12f);
  a0.x *= inv; a0.y *= inv; a0.z *= inv; a0.w *= inv;
  a1.x *= inv; a1.y *= inv; a1.z *= inv; a1.w *= inv;
  *(float4*)(p + lane * 8) = a0;
  *(float4*)(p + lane * 8 + 4) = a1;
  if (lane == 0) wout[row] = dot + fcb[0];
}

// ---------------- softmax: blocks 0..63 vw rows (196), 64..127 tw rows (64, masked) ----
__global__ void k_softmax(float* __restrict__ vwf, float* __restrict__ twf,
                          const int* __restrict__ tlen) {
  __shared__ float red[8];
  int tid = threadIdx.x;
  if (blockIdx.x < 64) {
    int b = blockIdx.x;
    float x = (tid < NV) ? vwf[b * NV + tid] : -1e30f;
    float m = x;
    for (int s = 1; s < 64; s <<= 1) m = fmaxf(m, __shfl_xor(m, s));
    if ((tid & 63) == 0) red[tid >> 6] = m;
    __syncthreads();
    m = fmaxf(fmaxf(red[0], red[1]), fmaxf(red[2], red[3]));
    float e = (tid < NV) ? expf(x - m) : 0.0f;
    float s = e;
    for (int st = 1; st < 64; st <<= 1) s += __shfl_xor(s, st);
    if ((tid & 63) == 0) red[4 + (tid >> 6)] = s;
    __syncthreads();
    s = red[4] + red[5] + red[6] + red[7];
    if (tid < NV) vwf[b * NV + tid] = e / s;
  } else {
    int b = blockIdx.x - 64;
    if (tid < 64) {
      int len = tlen[b];
      float x = twf[b * NT + tid];
      bool valid = tid < len;
      float xv = valid ? x : -1e30f;
      float m = xv;
      for (int s = 1; s < 64; s <<= 1) m = fmaxf(m, __shfl_xor(m, s));
      float e = valid ? expf(x - m) : 0.0f;
      float s = e;
      for (int st = 1; st < 64; st <<= 1) s += __shfl_xor(s, st);
      twf[b * NT + tid] = e / s;
    }
  }
}

// ---------------- sim kernel: one block per (b,q); fused max/argmax reductions ------
// 224 active threads: tv=tid>>3 (28 groups of 7 v-rows), tt=tid&7 (t = tt+8j)
__global__ __launch_bounds__(256, 2) void k_sim(
    const float* __restrict__ ven, const float* __restrict__ ten,
    const float* __restrict__ vwf, const float* __restrict__ twf,
    float* __restrict__ out, int* __restrict__ gMT, int* __restrict__ gMV) {
  __shared__ float As[NV * 36];
  __shared__ float Bs[NT * 36];
  __shared__ float colv[28 * 64];
  __shared__ int coli[28 * 64];
  __shared__ float rowp[28];
  int q = blockIdx.x, b = blockIdx.y;
  int tid = threadIdx.x;
  int tv = tid >> 3, tt = tid & 7;
  const float* Ab = ven + (size_t)b * NV * EDIM;
  const float* Bb = ten + (size_t)q * NT * EDIM;
  float acc[7][8] = {};
  for (int k0 = 0; k0 < EDIM; k0 += 32) {
    for (int u = tid; u < NV * 8; u += 256) {
      int v = u >> 3, kq = (u & 7) << 2;
      *(float4*)(As + v * 36 + kq) = *(const float4*)(Ab + (size_t)v * EDIM + k0 + kq);
    }
    for (int u = tid; u < NT * 8; u += 256) {
      int t = u >> 3, kq = (u & 7) << 2;
      *(float4*)(Bs + t * 36 + kq) = *(const float4*)(Bb + (size_t)t * EDIM + k0 + kq);
    }
    __syncthreads();
    if (tv < 28) {
      for (int k = 0; k < 32; k += 4) {
        float4 av[7], bt[8];
#pragma unroll
        for (int i = 0; i < 7; i++) av[i] = *(const float4*)(As + (tv * 7 + i) * 36 + k);
#pragma unroll
        for (int j = 0; j < 8; j++) bt[j] = *(const float4*)(Bs + (tt + 8 * j) * 36 + k);
#pragma unroll
        for (int i = 0; i < 7; i++)
#pragma unroll
          for (int j = 0; j < 8; j++)
            acc[i][j] += av[i].x * bt[j].x + av[i].y * bt[j].y +
                         av[i].z * bt[j].z + av[i].w * bt[j].w;
      }
    }
    __syncthreads();
  }
  bool diag = (b == q);
  if (tv < 28) {
    float p_i2t = 0.0f;
#pragma unroll
    for (int i = 0; i < 7; i++) {
      float m = acc[i][0];
      int bi = tt;
#pragma unroll
      for (int j = 1; j < 8; j++) {
        float v = acc[i][j];
        int t = tt + 8 * j;
        if (v > m) { m = v; bi = t; }
      }
#pragma unroll
      for (int s = 1; s < 8; s <<= 1) {  // stays within aligned 8-lane group
        float om = __shfl_xor(m, s);
        int ob = __shfl_xor(bi, s);
        if (om > m || (om == m && ob < bi)) { m = om; bi = ob; }  // first-index ties
      }
      if (tt == 0) {
        int v = tv * 7 + i;
        p_i2t += vwf[b * NV + v] * m;
        if (diag) gMT[b * NV + v] = b * NT + bi;
      }
    }
    if (tt == 0) rowp[tv] = p_i2t;
#pragma unroll
    for (int j = 0; j < 8; j++) {
      float m = acc[0][j];
      int bi = tv * 7;
#pragma unroll
      for (int i = 1; i < 7; i++) {
        float v = acc[i][j];
        if (v > m) { m = v; bi = tv * 7 + i; }
      }
      colv[tv * 64 + tt + 8 * j] = m;
      coli[tv * 64 + tt + 8 * j] = bi;
    }
  }
  __syncthreads();
  if (tid < 64) {
    int t = tid;
    float m = colv[t];
    int bi = coli[t];
    for (int g = 1; g < 28; g++) {  // ascending v-blocks => first-index ties kept
      float v = colv[g * 64 + t];
      if (v > m) { m = v; bi = coli[g * 64 + t]; }
    }
    float p = twf[q * NT + t] * m;
    for (int s = 1; s < 64; s <<= 1) p += __shfl_xor(p, s);
    if (t == 0) out[4096 + b * 64 + q] = p;
    if (diag) gMV[b * NT + t] = b * NV + bi;
  }
  if (tid == 0) {
    float s = 0.0f;
    for (int g = 0; g < 28; g++) s += rowp[g];
    out[b * 64 + q] = s;
  }
}

// ---------------- column stats (sum, sumsq, weighted sum) with optional gather ------
__global__ void k_stats(const float* __restrict__ ven, const float* __restrict__ ten,
                        const int* __restrict__ gMT, const int* __restrict__ gMV,
                        const float* __restrict__ vwf, const float* __restrict__ twf,
                        float* __restrict__ statPart) {
  int stripe = blockIdx.x, chunk = blockIdx.y, m = blockIdx.z;
  int R = (m < 2) ? MROWS_T : MROWS_V;
  int nchunk = (R + 1023) >> 10;
  if (chunk >= nchunk) return;
  const float* M; const int* g; const float* w;
  if (m == 0)      { M = ten; g = 0;   w = twf; }
  else if (m == 1) { M = ven; g = gMV; w = twf; }
  else if (m == 2) { M = ven; g = 0;   w = vwf; }
  else             { M = ten; g = gMT; w = vwf; }
  int col = stripe * 64 + (threadIdx.x & 63);
  int rg = threadIdx.x >> 6;
  int r0 = chunk << 10;
  int r1 = min(r0 + 1024, R);
  float s = 0, ss = 0, sw = 0;
  for (int r = r0 + rg; r < r1; r += 4) {
    int row = g ? g[r] : r;
    float x = M[(size_t)row * EDIM + col];
    s += x; ss += x * x; sw += w[r] * x;
  }
  __shared__ float red[3][256];
  red[0][threadIdx.x] = s; red[1][threadIdx.x] = ss; red[2][threadIdx.x] = sw;
  __syncthreads();
  if (threadIdx.x < 64) {
    int c = threadIdx.x;
    float S  = red[0][c] + red[0][c + 64] + red[0][c + 128] + red[0][c + 192];
    float SS = red[1][c] + red[1][c + 64] + red[1][c + 128] + red[1][c + 192];
    float SW = red[2][c] + red[2][c + 64] + red[2][c + 128] + red[2][c + 192];
    size_t idx = ((size_t)(m * 13 + chunk) * 512 + stripe * 64 + c) * 3;
    statPart[idx] = S; statPart[idx + 1] = SS; statPart[idx + 2] = SW;
  }
}

__global__ void k_statfin(const float* __restrict__ statPart, float* __restrict__ stats) {
  int m = blockIdx.x, c = threadIdx.x;
  int R = (m < 2) ? MROWS_T : MROWS_V;
  int nchunk = (R + 1023) >> 10;
  float s = 0, ss = 0, sw = 0;
  for (int ch = 0; ch < nchunk; ch++) {
    size_t idx = ((size_t)(m * 13 + ch) * 512 + c) * 3;
    s += statPart[idx]; ss += statPart[idx + 1]; sw += statPart[idx + 2];
  }
  float mean = s / R;
  float var = (ss - s * mean) / (R - 1);  // ddof=1, matches torch-style .std()
  float rstd = 1.0f / sqrtf(var);
  stats[(m * 3 + 0) * 512 + c] = mean;
  stats[(m * 3 + 1) * 512 + c] = rstd;
  stats[(m * 3 + 2) * 512 + c] = sw;
}

// ------- weighted split-K GEMM: S[c,d] = sum_a w[a]*A[a,c]*B[g[a],d] (8 K-slices) ----
__global__ __launch_bounds__(256, 2) void k_wgemm(
    const float* __restrict__ ven, const float* __restrict__ ten,
    const int* __restrict__ gMT, const int* __restrict__ gMV,
    const float* __restrict__ vwf, const float* __restrict__ twf,
    float* __restrict__ Spart) {
  __shared__ float Asl[64 * 128];
  __shared__ float Bsl[64 * 64];
  int ct = blockIdx.x, dt = blockIdx.y, zz = blockIdx.z;
  int which = zz >> 3, slice = zz & 7;
  const float* A; const float* Bm; const int* g; const float* w; int K;
  if (which == 0) { A = ten; Bm = ven; g = gMV; w = twf; K = MROWS_T; }
  else            { A = ven; Bm = ten; g = gMT; w = vwf; K = MROWS_V; }
  int aStart = slice * (K >> 3), aEnd = aStart + (K >> 3);
  int tid = threadIdx.x, ty = tid >> 4, tx = tid & 15;
  int c0 = ct * 128, d0 = dt * 64;
  float acc[8][4] = {};
  for (int a0 = aStart; a0 < aEnd; a0 += 64) {
    int asz = min(64, aEnd - a0);
    for (int u = tid; u < 64 * 32; u += 256) {
      int a = u >> 5, cq = (u & 31) << 2;
      float4 v = make_float4(0.f, 0.f, 0.f, 0.f);
      if (a < asz) {
        v = *(const float4*)(A + (size_t)(a0 + a) * EDIM + c0 + cq);
        float wa = w[a0 + a];
        v.x *= wa; v.y *= wa; v.z *= wa; v.w *= wa;
      }
      *(float4*)(Asl + a * 128 + cq) = v;
    }
    for (int u = tid; u < 64 * 16; u += 256) {
      int a = u >> 4, dq = (u & 15) << 2;
      float4 v = make_float4(0.f, 0.f, 0.f, 0.f);
      if (a < asz) {
        int row = g[a0 + a];
        v = *(const float4*)(Bm + (size_t)row * EDIM + d0 + dq);
      }
      *(float4*)(Bsl + a * 64 + dq) = v;
    }
    __syncthreads();
    for (int a = 0; a < 64; a++) {
      float4 a0v = *(const float4*)(Asl + a * 128 + ty * 8);
      float4 a1v = *(const float4*)(Asl + a * 128 + ty * 8 + 4);
      float4 bv = *(const float4*)(Bsl + a * 64 + tx * 4);
      float aa[8] = {a0v.x, a0v.y, a0v.z, a0v.w, a1v.x, a1v.y, a1v.z, a1v.w};
#pragma unroll
      for (int i = 0; i < 8; i++) {
        acc[i][0] += aa[i] * bv.x;
        acc[i][1] += aa[i] * bv.y;
        acc[i][2] += aa[i] * bv.z;
        acc[i][3] += aa[i] * bv.w;
      }
    }
    __syncthreads();
  }
  float* outp = Spart + (size_t)(which * 8 + slice) * 512 * 512;
#pragma unroll
  for (int i = 0; i < 8; i++) {
    int c = c0 + ty * 8 + i;
    float4 v = make_float4(acc[i][0], acc[i][1], acc[i][2], acc[i][3]);
    *(float4*)(outp + (size_t)c * 512 + d0 + tx * 4) = v;
  }
}

// ---------------- assemble c = (c1+c2)/2 from closed form; loss partials ----------
__global__ void k_assemble(const float* __restrict__ Spart, const float* __restrict__ stats,
                           float* __restrict__ lossPart) {
  int c = blockIdx.x, tid = threadIdx.x;
  float muT = stats[0 * 512 + c], rsT = stats[1 * 512 + c], swT = stats[2 * 512 + c];
  float muV = stats[6 * 512 + c], rsV = stats[7 * 512 + c], swV = stats[8 * 512 + c];
  const float W = 64.0f, invB = 1.0f / 64.0f;
  float on = 0, off = 0;
  for (int d = tid; d < 512; d += 256) {
    float s1 = 0, s2 = 0;
    for (int sl = 0; sl < 8; sl++) {
      s1 += Spart[((size_t)sl * 512 + c) * 512 + d];
      s2 += Spart[((size_t)(8 + sl) * 512 + c) * 512 + d];
    }
    float muMV = stats[3 * 512 + d], rsMV = stats[4 * 512 + d], swMV = stats[5 * 512 + d];
    float muMT = stats[9 * 512 + d], rsMT = stats[10 * 512 + d], swMT = stats[11 * 512 + d];
    float c1 = (s1 - muT * swMV - muMV * swT + muT * muMV * W) * rsT * rsMV * invB;
    float c2 = (s2 - muV * swMT - muMT * swV + muV * muMT * W) * rsV * rsMT * invB;
    float cc = 0.5f * (c1 + c2);
    if (d == c) { float dd = cc - 1.0f; on += dd * dd; }
    else off += cc * cc;
  }
  __shared__ float r1[4], r2[4];
  for (int s = 1; s < 64; s <<= 1) { on += __shfl_xor(on, s); off += __shfl_xor(off, s); }
  if ((tid & 63) == 0) { r1[tid >> 6] = on; r2[tid >> 6] = off; }
  __syncthreads();
  if (tid == 0) {
    lossPart[c * 2] = r1[0] + r1[1] + r1[2] + r1[3];
    lossPart[c * 2 + 1] = r2[0] + r2[1] + r2[2] + r2[3];
  }
}

__global__ void k_loss(const float* __restrict__ lossPart, float* __restrict__ out) {
  int tid = threadIdx.x;
  float on = 0, off = 0;
  for (int i = tid; i < 512; i += 256) { on += lossPart[2 * i]; off += lossPart[2 * i + 1]; }
  __shared__ float r1[4], r2[4];
  for (int s = 1; s < 64; s <<= 1) { on += __shfl_xor(on, s); off += __shfl_xor(off, s); }
  if ((tid & 63) == 0) { r1[tid >> 6] = on; r2[tid >> 6] = off; }
  __syncthreads();
  if (tid == 0)
    out[8192] = 0.1f * ((r1[0] + r1[1] + r1[2] + r1[3]) +
                        0.06f * (r2[0] + r2[1] + r2[2] + r2[3]));
}

extern "C" void kernel_launch(void* const* d_in, const int* in_sizes, int n_in,
                              void* d_out, int out_size, void* d_ws, size_t ws_size,
                              hipStream_t stream) {
  (void)in_sizes; (void)n_in; (void)out_size; (void)ws_size;
  const float* v_tok  = (const float*)d_in[1];
  const float* t_tok  = (const float*)d_in[3];
  const float* Wv_tok = (const float*)d_in[8];
  const float* bv_tok = (const float*)d_in[9];
  const float* Wt_tok = (const float*)d_in[10];
  const float* bt_tok = (const float*)d_in[11];
  const float* wv_fc  = (const float*)d_in[12];
  const float* bv_fc  = (const float*)d_in[13];
  const float* wt_fc  = (const float*)d_in[14];
  const float* bt_fc  = (const float*)d_in[15];
  const int*   tlen   = (const int*)d_in[16];
  float* out = (float*)d_out;

  // workspace layout (floats), total ~= 13.62M floats ~= 54.5 MB
  float* ws = (float*)d_ws;
  float* ve = ws;                         // 12544*512
  float* te = ve + (size_t)12544 * 512;   // 4096*512
  float* Wvt = te + (size_t)4096 * 512;   // 512*768
  float* Wtt = Wvt + (size_t)512 * 768;   // 512*768
  float* vwf = Wtt + (size_t)512 * 768;   // 12544
  float* twf = vwf + 12544;               // 4096
  int* gMT = (int*)(twf + 4096);          // 12544
  int* gMV = gMT + 12544;                 // 4096
  float* Spart = (float*)(gMV + 4096);    // 16*512*512
  float* statPart = Spart + (size_t)16 * 512 * 512;  // 4*13*512*3
  float* stats = statPart + 4 * 13 * 512 * 3;        // 12*512
  float* lossPart = stats + 12 * 512;                // 1024

  k_transpose<<<dim3(24, 16, 2), dim3(32, 8), 0, stream>>>(Wv_tok, Wt_tok, Wvt, Wtt);
  k_proj<<<dim3(8, 98), 256, 0, stream>>>(v_tok, Wvt, bv_tok, ve);
  k_proj<<<dim3(8, 32), 256, 0, stream>>>(t_tok, Wtt, bt_tok, te);
  k_normfc<<<3136, 256, 0, stream>>>(ve, wv_fc, bv_fc, vwf, 12544);
  k_normfc<<<1024, 256, 0, stream>>>(te, wt_fc, bt_fc, twf, 4096);
  k_softmax<<<128, 256, 0, stream>>>(vwf, twf, tlen);
  k_sim<<<dim3(64, 64), 256, 0, stream>>>(ve, te, vwf, twf, out, gMT, gMV);
  k_stats<<<dim3(8, 13, 4), 256, 0, stream>>>(ve, te, gMT, gMV, vwf, twf, statPart);
  k_statfin<<<4, 512, 0, stream>>>(statPart, stats);
  k_wgemm<<<dim3(4, 8, 16), 256, 0, stream>>>(ve, te, gMT, gMV, vwf, twf, Spart);
  k_assemble<<<512, 256, 0, stream>>>(Spart, stats, lossPart);
  k_loss<<<1, 256, 0, stream>>>(lossPart, out);
}

// Round 2
// 854.235 us; speedup vs baseline: 2.0706x; 2.0706x over previous
//
#include <hip/hip_runtime.h>
#include <cstddef>

#define EDIM 512
#define KDIM 768
#define NB 64
#define NV 196
#define NT 64
#define MROWS_V (NB * NV) /* 12544 */
#define MROWS_T (NB * NT) /* 4096  */

typedef __attribute__((ext_vector_type(8))) short bf16x8;
typedef __attribute__((ext_vector_type(4))) float f32x4;

static __device__ inline unsigned short f2bf(float f) {  // round-to-nearest-even
  unsigned u = __float_as_uint(f);
  unsigned r = (u + 0x7fff + ((u >> 16) & 1)) >> 16;
  return (unsigned short)r;
}

// ---------------- transpose W [768x512] -> Wt [512x768] ----------------
__global__ void k_transpose(const float* __restrict__ W0, const float* __restrict__ W1,
                            float* __restrict__ T0, float* __restrict__ T1) {
  __shared__ float tile[32][33];
  const float* W = blockIdx.z ? W1 : W0;
  float*       T = blockIdx.z ? T1 : T0;
  int k0 = blockIdx.x * 32;
  int n0 = blockIdx.y * 32;
  int tx = threadIdx.x, ty = threadIdx.y;
  for (int i = ty; i < 32; i += 8)
    tile[i][tx] = W[(size_t)(k0 + i) * EDIM + n0 + tx];
  __syncthreads();
  for (int i = ty; i < 32; i += 8)
    T[(size_t)(n0 + i) * KDIM + k0 + tx] = tile[tx][i];
}

// ---------- projection GEMM: C[r,n] = sum_k X[r,k]*Wt[n,k] + bias[n] ----------
__global__ __launch_bounds__(256, 2) void k_proj(const float* __restrict__ X,
                                                 const float* __restrict__ Wt,
                                                 const float* __restrict__ bias,
                                                 float* __restrict__ C) {
  __shared__ float Xs[128 * 68];
  __shared__ float Ws[64 * 68];
  int n0 = blockIdx.x * 64;
  int r0 = blockIdx.y * 128;
  int tid = threadIdx.x;
  int ty = tid >> 4, tx = tid & 15;
  float acc[8][4] = {};
  for (int k0 = 0; k0 < KDIM; k0 += 64) {
    for (int u = tid; u < 128 * 16; u += 256) {
      int r = u >> 4, kq = (u & 15) << 2;
      *(float4*)(Xs + r * 68 + kq) =
          *(const float4*)(X + (size_t)(r0 + r) * KDIM + k0 + kq);
    }
    for (int u = tid; u < 64 * 16; u += 256) {
      int n = u >> 4, kq = (u & 15) << 2;
      *(float4*)(Ws + n * 68 + kq) =
          *(const float4*)(Wt + (size_t)(n0 + n) * KDIM + k0 + kq);
    }
    __syncthreads();
    for (int k = 0; k < 64; k += 4) {
      float4 xa[8], wb[4];
#pragma unroll
      for (int i = 0; i < 8; i++) xa[i] = *(const float4*)(Xs + (ty + 16 * i) * 68 + k);
#pragma unroll
      for (int j = 0; j < 4; j++) wb[j] = *(const float4*)(Ws + (tx + 16 * j) * 68 + k);
#pragma unroll
      for (int i = 0; i < 8; i++)
#pragma unroll
        for (int j = 0; j < 4; j++)
          acc[i][j] += xa[i].x * wb[j].x + xa[i].y * wb[j].y +
                       xa[i].z * wb[j].z + xa[i].w * wb[j].w;
    }
    __syncthreads();
  }
#pragma unroll
  for (int j = 0; j < 4; j++) {
    int n = n0 + tx + 16 * j;
    float bb = bias[n];
#pragma unroll
    for (int i = 0; i < 8; i++)
      C[(size_t)(r0 + ty + 16 * i) * EDIM + n] = acc[i][j] + bb;
  }
}

// ------- per-row: fc scalar (pre-norm) + l2 normalize in place + bf16 copy -------
__global__ void k_normfc(float* __restrict__ M, const float* __restrict__ fcw,
                         const float* __restrict__ fcb, float* __restrict__ wout,
                         short* __restrict__ Mbf, int nrows) {
  int row = blockIdx.x * 4 + (threadIdx.x >> 6);
  int lane = threadIdx.x & 63;
  if (row >= nrows) return;
  float* p = M + (size_t)row * EDIM;
  float4 a0 = *(float4*)(p + lane * 8);
  float4 a1 = *(float4*)(p + lane * 8 + 4);
  float4 w0 = *(const float4*)(fcw + lane * 8);
  float4 w1 = *(const float4*)(fcw + lane * 8 + 4);
  float dot = a0.x * w0.x + a0.y * w0.y + a0.z * w0.z + a0.w * w0.w +
              a1.x * w1.x + a1.y * w1.y + a1.z * w1.z + a1.w * w1.w;
  float ss = a0.x * a0.x + a0.y * a0.y + a0.z * a0.z + a0.w * a0.w +
             a1.x * a1.x + a1.y * a1.y + a1.z * a1.z + a1.w * a1.w;
  for (int s = 1; s < 64; s <<= 1) {
    dot += __shfl_xor(dot, s);
    ss += __shfl_xor(ss, s);
  }
  float inv = 1.0f / fmaxf(sqrtf(ss), 1e-12f);
  a0.x *= inv; a0.y *= inv; a0.z *= inv; a0.w *= inv;
  a1.x *= inv; a1.y *= inv; a1.z *= inv; a1.w *= inv;
  *(float4*)(p + lane * 8) = a0;
  *(float4*)(p + lane * 8 + 4) = a1;
  bf16x8 bv;
  bv[0] = (short)f2bf(a0.x); bv[1] = (short)f2bf(a0.y);
  bv[2] = (short)f2bf(a0.z); bv[3] = (short)f2bf(a0.w);
  bv[4] = (short)f2bf(a1.x); bv[5] = (short)f2bf(a1.y);
  bv[6] = (short)f2bf(a1.z); bv[7] = (short)f2bf(a1.w);
  *(bf16x8*)(Mbf + (size_t)row * EDIM + lane * 8) = bv;
  if (lane == 0) wout[row] = dot + fcb[0];
}

// ---------------- softmax: blocks 0..63 vw rows (196), 64..127 tw rows (64, masked) ----
__global__ void k_softmax(float* __restrict__ vwf, float* __restrict__ twf,
                          const int* __restrict__ tlen) {
  __shared__ float red[8];
  int tid = threadIdx.x;
  if (blockIdx.x < 64) {
    int b = blockIdx.x;
    float x = (tid < NV) ? vwf[b * NV + tid] : -1e30f;
    float m = x;
    for (int s = 1; s < 64; s <<= 1) m = fmaxf(m, __shfl_xor(m, s));
    if ((tid & 63) == 0) red[tid >> 6] = m;
    __syncthreads();
    m = fmaxf(fmaxf(red[0], red[1]), fmaxf(red[2], red[3]));
    float e = (tid < NV) ? expf(x - m) : 0.0f;
    float s = e;
    for (int st = 1; st < 64; st <<= 1) s += __shfl_xor(s, st);
    if ((tid & 63) == 0) red[4 + (tid >> 6)] = s;
    __syncthreads();
    s = red[4] + red[5] + red[6] + red[7];
    if (tid < NV) vwf[b * NV + tid] = e / s;
  } else {
    int b = blockIdx.x - 64;
    if (tid < 64) {
      int len = tlen[b];
      float x = twf[b * NT + tid];
      bool valid = tid < len;
      float xv = valid ? x : -1e30f;
      float m = xv;
      for (int s = 1; s < 64; s <<= 1) m = fmaxf(m, __shfl_xor(m, s));
      float e = valid ? expf(x - m) : 0.0f;
      float s = e;
      for (int st = 1; st < 64; st <<= 1) s += __shfl_xor(s, st);
      twf[b * NT + tid] = e / s;
    }
  }
}

// ---------------- MFMA sim kernel: one block (4 waves) per (b,q) --------------------
// Wave w owns col-tile w (16 t's). 13 row-tiles of 16 v's (196 padded to 208).
// S = ve[b] (196x512) . te[q]^T (512x64), bf16 in / f32 acc, fused max/argmax.
__global__ __launch_bounds__(256, 2) void k_sim(
    const short* __restrict__ ve_bf, const short* __restrict__ te_bf,
    const float* __restrict__ vwf, const float* __restrict__ twf,
    float* __restrict__ out, int* __restrict__ gMT, int* __restrict__ gMV) {
  __shared__ short As[208 * 40];   // 80 B/row: 32 bf16 + 8 pad (bank-conflict-free)
  __shared__ short Bs[64 * 40];
  __shared__ float rowv[196 * 4];
  __shared__ int   rowi[196 * 4];
  __shared__ float colpart[64];
  __shared__ float redp[4];
  int q = blockIdx.x, b = blockIdx.y;
  int tid = threadIdx.x;
  int w = tid >> 6, lane = tid & 63;
  int lg = lane >> 4, li = lane & 15;
  const short* Abf = ve_bf + (size_t)b * NV * EDIM;
  const short* Bbf = te_bf + (size_t)q * NT * EDIM;
  f32x4 acc[13];
#pragma unroll
  for (int r = 0; r < 13; ++r) acc[r] = (f32x4){0.f, 0.f, 0.f, 0.f};

  for (int kc = 0; kc < 16; ++kc) {
    int k0 = kc << 5;
    __syncthreads();  // previous chunk's reads done before overwrite
    {   // B: 64 rows x 4 segs = 256 units, one per thread
      int t = tid >> 2, seg = tid & 3;
      *(int4*)(Bs + t * 40 + seg * 8) = *(const int4*)(Bbf + (size_t)t * EDIM + k0 + seg * 8);
    }
    for (int u = tid; u < NV * 4; u += 256) {  // A: 196 rows x 4 segs (pad rows stale, masked)
      int v = u >> 2, seg = u & 3;
      *(int4*)(As + v * 40 + seg * 8) = *(const int4*)(Abf + (size_t)v * EDIM + k0 + seg * 8);
    }
    __syncthreads();
    bf16x8 bfrag = *(const bf16x8*)(Bs + (w * 16 + li) * 40 + lg * 8);
#pragma unroll
    for (int r = 0; r < 13; ++r) {
      bf16x8 afrag = *(const bf16x8*)(As + (r * 16 + li) * 40 + lg * 8);
      acc[r] = __builtin_amdgcn_mfma_f32_16x16x32_bf16(afrag, bfrag, acc[r], 0, 0, 0);
    }
  }

  bool diag = (b == q);
  // ---- row (over t) max+argmax within this wave's 16 t's; C layout: v=r*16+lg*4+reg, t=w*16+li
#pragma unroll
  for (int r = 0; r < 13; ++r) {
#pragma unroll
    for (int reg = 0; reg < 4; ++reg) {
      int v = r * 16 + lg * 4 + reg;
      float m = acc[r][reg];
      int ti = w * 16 + li;
      for (int d = 1; d < 16; d <<= 1) {
        float om = __shfl_xor(m, d);
        int oi = __shfl_xor(ti, d);
        if (om > m || (om == m && oi < ti)) { m = om; ti = oi; }
      }
      if (li == 0 && v < NV) { rowv[v * 4 + w] = m; rowi[v * 4 + w] = ti; }
    }
  }
  // ---- col (over v) max+argmax for this wave's 16 t's
  {
    float cm = -__builtin_huge_valf();
    int cv = 0;
#pragma unroll
    for (int r = 0; r < 13; ++r) {
#pragma unroll
      for (int reg = 0; reg < 4; ++reg) {
        int v = r * 16 + lg * 4 + reg;
        float s = (v < NV) ? acc[r][reg] : -__builtin_huge_valf();
        if (s > cm) { cm = s; cv = v; }  // v ascending -> first-index kept
      }
    }
    for (int d = 16; d < 64; d <<= 1) {
      float om = __shfl_xor(cm, d);
      int ov = __shfl_xor(cv, d);
      if (om > cm || (om == cm && ov < cv)) { cm = om; cv = ov; }
    }
    int t = w * 16 + li;
    if (lg == 0) {
      if (diag) gMV[b * NT + t] = b * NV + cv;
      colpart[t] = twf[q * NT + t] * cm;
    }
  }
  __syncthreads();
  // ---- combine row maxima across 4 waves; weighted i2t sum
  float ip = 0.f;
  if (tid < NV) {
    float m = rowv[tid * 4];
    int ti = rowi[tid * 4];
#pragma unroll
    for (int w2 = 1; w2 < 4; ++w2) {
      float om = rowv[tid * 4 + w2];
      int oi = rowi[tid * 4 + w2];
      if (om > m || (om == m && oi < ti)) { m = om; ti = oi; }
    }
    if (diag) gMT[b * NV + tid] = b * NT + ti;
    ip = vwf[b * NV + tid] * m;
  }
  for (int d = 1; d < 64; d <<= 1) ip += __shfl_xor(ip, d);
  if (lane == 0) redp[w] = ip;
  if (w == 1) {  // t2i: sum tw-weighted col maxima (colpart valid since barrier above)
    float p = colpart[lane];
    for (int d = 1; d < 64; d <<= 1) p += __shfl_xor(p, d);
    if (lane == 0) out[4096 + b * 64 + q] = p;
  }
  __syncthreads();
  if (tid == 0) out[b * 64 + q] = redp[0] + redp[1] + redp[2] + redp[3];
}

// ---------------- column stats (sum, sumsq, weighted sum) with optional gather ------
__global__ void k_stats(const float* __restrict__ ven, const float* __restrict__ ten,
                        const int* __restrict__ gMT, const int* __restrict__ gMV,
                        const float* __restrict__ vwf, const float* __restrict__ twf,
                        float* __restrict__ statPart) {
  int stripe = blockIdx.x, chunk = blockIdx.y, m = blockIdx.z;
  int R = (m < 2) ? MROWS_T : MROWS_V;
  int nchunk = (R + 1023) >> 10;
  if (chunk >= nchunk) return;
  const float* M; const int* g; const float* w;
  if (m == 0)      { M = ten; g = 0;   w = twf; }
  else if (m == 1) { M = ven; g = gMV; w = twf; }
  else if (m == 2) { M = ven; g = 0;   w = vwf; }
  else             { M = ten; g = gMT; w = vwf; }
  int col = stripe * 64 + (threadIdx.x & 63);
  int rg = threadIdx.x >> 6;
  int r0 = chunk << 10;
  int r1 = min(r0 + 1024, R);
  float s = 0, ss = 0, sw = 0;
  for (int r = r0 + rg; r < r1; r += 4) {
    int row = g ? g[r] : r;
    float x = M[(size_t)row * EDIM + col];
    s += x; ss += x * x; sw += w[r] * x;
  }
  __shared__ float red[3][256];
  red[0][threadIdx.x] = s; red[1][threadIdx.x] = ss; red[2][threadIdx.x] = sw;
  __syncthreads();
  if (threadIdx.x < 64) {
    int c = threadIdx.x;
    float S  = red[0][c] + red[0][c + 64] + red[0][c + 128] + red[0][c + 192];
    float SS = red[1][c] + red[1][c + 64] + red[1][c + 128] + red[1][c + 192];
    float SW = red[2][c] + red[2][c + 64] + red[2][c + 128] + red[2][c + 192];
    size_t idx = ((size_t)(m * 13 + chunk) * 512 + stripe * 64 + c) * 3;
    statPart[idx] = S; statPart[idx + 1] = SS; statPart[idx + 2] = SW;
  }
}

__global__ void k_statfin(const float* __restrict__ statPart, float* __restrict__ stats) {
  int m = blockIdx.x, c = threadIdx.x;
  int R = (m < 2) ? MROWS_T : MROWS_V;
  int nchunk = (R + 1023) >> 10;
  float s = 0, ss = 0, sw = 0;
  for (int ch = 0; ch < nchunk; ch++) {
    size_t idx = ((size_t)(m * 13 + ch) * 512 + c) * 3;
    s += statPart[idx]; ss += statPart[idx + 1]; sw += statPart[idx + 2];
  }
  float mean = s / R;
  float var = (ss - s * mean) / (R - 1);  // ddof=1
  float rstd = 1.0f / sqrtf(var);
  stats[(m * 3 + 0) * 512 + c] = mean;
  stats[(m * 3 + 1) * 512 + c] = rstd;
  stats[(m * 3 + 2) * 512 + c] = sw;
}

// ------- weighted split-K GEMM: S[c,d] = sum_a w[a]*A[a,c]*B[g[a],d] (8 K-slices) ----
__global__ __launch_bounds__(256, 2) void k_wgemm(
    const float* __restrict__ ven, const float* __restrict__ ten,
    const int* __restrict__ gMT, const int* __restrict__ gMV,
    const float* __restrict__ vwf, const float* __restrict__ twf,
    float* __restrict__ Spart) {
  __shared__ float Asl[64 * 128];
  __shared__ float Bsl[64 * 64];
  int ct = blockIdx.x, dt = blockIdx.y, zz = blockIdx.z;
  int which = zz >> 3, slice = zz & 7;
  const float* A; const float* Bm; const int* g; const float* w; int K;
  if (which == 0) { A = ten; Bm = ven; g = gMV; w = twf; K = MROWS_T; }
  else            { A = ven; Bm = ten; g = gMT; w = vwf; K = MROWS_V; }
  int aStart = slice * (K >> 3), aEnd = aStart + (K >> 3);
  int tid = threadIdx.x, ty = tid >> 4, tx = tid & 15;
  int c0 = ct * 128, d0 = dt * 64;
  float acc[8][4] = {};
  for (int a0 = aStart; a0 < aEnd; a0 += 64) {
    int asz = min(64, aEnd - a0);
    for (int u = tid; u < 64 * 32; u += 256) {
      int a = u >> 5, cq = (u & 31) << 2;
      float4 v = make_float4(0.f, 0.f, 0.f, 0.f);
      if (a < asz) {
        v = *(const float4*)(A + (size_t)(a0 + a) * EDIM + c0 + cq);
        float wa = w[a0 + a];
        v.x *= wa; v.y *= wa; v.z *= wa; v.w *= wa;
      }
      *(float4*)(Asl + a * 128 + cq) = v;
    }
    for (int u = tid; u < 64 * 16; u += 256) {
      int a = u >> 4, dq = (u & 15) << 2;
      float4 v = make_float4(0.f, 0.f, 0.f, 0.f);
      if (a < asz) {
        int row = g[a0 + a];
        v = *(const float4*)(Bm + (size_t)row * EDIM + d0 + dq);
      }
      *(float4*)(Bsl + a * 64 + dq) = v;
    }
    __syncthreads();
    for (int a = 0; a < 64; a++) {
      float4 a0v = *(const float4*)(Asl + a * 128 + ty * 8);
      float4 a1v = *(const float4*)(Asl + a * 128 + ty * 8 + 4);
      float4 bv = *(const float4*)(Bsl + a * 64 + tx * 4);
      float aa[8] = {a0v.x, a0v.y, a0v.z, a0v.w, a1v.x, a1v.y, a1v.z, a1v.w};
#pragma unroll
      for (int i = 0; i < 8; i++) {
        acc[i][0] += aa[i] * bv.x;
        acc[i][1] += aa[i] * bv.y;
        acc[i][2] += aa[i] * bv.z;
        acc[i][3] += aa[i] * bv.w;
      }
    }
    __syncthreads();
  }
  float* outp = Spart + (size_t)(which * 8 + slice) * 512 * 512;
#pragma unroll
  for (int i = 0; i < 8; i++) {
    int c = c0 + ty * 8 + i;
    float4 v = make_float4(acc[i][0], acc[i][1], acc[i][2], acc[i][3]);
    *(float4*)(outp + (size_t)c * 512 + d0 + tx * 4) = v;
  }
}

// ---------------- assemble c = (c1+c2)/2 from closed form; loss partials ----------
__global__ void k_assemble(const float* __restrict__ Spart, const float* __restrict__ stats,
                           float* __restrict__ lossPart) {
  int c = blockIdx.x, tid = threadIdx.x;
  float muT = stats[0 * 512 + c], rsT = stats[1 * 512 + c], swT = stats[2 * 512 + c];
  float muV = stats[6 * 512 + c], rsV = stats[7 * 512 + c], swV = stats[8 * 512 + c];
  const float W = 64.0f, invB = 1.0f / 64.0f;
  float on = 0, off = 0;
  for (int d = tid; d < 512; d += 256) {
    float s1 = 0, s2 = 0;
    for (int sl = 0; sl < 8; sl++) {
      s1 += Spart[((size_t)sl * 512 + c) * 512 + d];
      s2 += Spart[((size_t)(8 + sl) * 512 + c) * 512 + d];
    }
    float muMV = stats[3 * 512 + d], rsMV = stats[4 * 512 + d], swMV = stats[5 * 512 + d];
    float muMT = stats[9 * 512 + d], rsMT = stats[10 * 512 + d], swMT = stats[11 * 512 + d];
    float c1 = (s1 - muT * swMV - muMV * swT + muT * muMV * W) * rsT * rsMV * invB;
    float c2 = (s2 - muV * swMT - muMT * swV + muV * muMT * W) * rsV * rsMT * invB;
    float cc = 0.5f * (c1 + c2);
    if (d == c) { float dd = cc - 1.0f; on += dd * dd; }
    else off += cc * cc;
  }
  __shared__ float r1[4], r2[4];
  for (int s = 1; s < 64; s <<= 1) { on += __shfl_xor(on, s); off += __shfl_xor(off, s); }
  if ((tid & 63) == 0) { r1[tid >> 6] = on; r2[tid >> 6] = off; }
  __syncthreads();
  if (tid == 0) {
    lossPart[c * 2] = r1[0] + r1[1] + r1[2] + r1[3];
    lossPart[c * 2 + 1] = r2[0] + r2[1] + r2[2] + r2[3];
  }
}

__global__ void k_loss(const float* __restrict__ lossPart, float* __restrict__ out) {
  int tid = threadIdx.x;
  float on = 0, off = 0;
  for (int i = tid; i < 512; i += 256) { on += lossPart[2 * i]; off += lossPart[2 * i + 1]; }
  __shared__ float r1[4], r2[4];
  for (int s = 1; s < 64; s <<= 1) { on += __shfl_xor(on, s); off += __shfl_xor(off, s); }
  if ((tid & 63) == 0) { r1[tid >> 6] = on; r2[tid >> 6] = off; }
  __syncthreads();
  if (tid == 0)
    out[8192] = 0.1f * ((r1[0] + r1[1] + r1[2] + r1[3]) +
                        0.06f * (r2[0] + r2[1] + r2[2] + r2[3]));
}

extern "C" void kernel_launch(void* const* d_in, const int* in_sizes, int n_in,
                              void* d_out, int out_size, void* d_ws, size_t ws_size,
                              hipStream_t stream) {
  (void)in_sizes; (void)n_in; (void)out_size; (void)ws_size;
  const float* v_tok  = (const float*)d_in[1];
  const float* t_tok  = (const float*)d_in[3];
  const float* Wv_tok = (const float*)d_in[8];
  const float* bv_tok = (const float*)d_in[9];
  const float* Wt_tok = (const float*)d_in[10];
  const float* bt_tok = (const float*)d_in[11];
  const float* wv_fc  = (const float*)d_in[12];
  const float* bv_fc  = (const float*)d_in[13];
  const float* wt_fc  = (const float*)d_in[14];
  const float* bt_fc  = (const float*)d_in[15];
  const int*   tlen   = (const int*)d_in[16];
  float* out = (float*)d_out;

  float* ws = (float*)d_ws;
  float* ve = ws;                         // 12544*512
  float* te = ve + (size_t)12544 * 512;   // 4096*512
  float* Wvt = te + (size_t)4096 * 512;   // 512*768
  float* Wtt = Wvt + (size_t)512 * 768;   // 512*768
  float* vwf = Wtt + (size_t)512 * 768;   // 12544
  float* twf = vwf + 12544;               // 4096
  int* gMT = (int*)(twf + 4096);          // 12544
  int* gMV = gMT + 12544;                 // 4096
  float* Spart = (float*)(gMV + 4096);    // 16*512*512
  float* statPart = Spart + (size_t)16 * 512 * 512;  // 4*13*512*3
  float* stats = statPart + 4 * 13 * 512 * 3;        // 12*512
  float* lossPart = stats + 12 * 512;                // 1024

  // bf16 copies overlay Spart+statPart (lifetime-disjoint: consumed by k_sim,
  // Spart/statPart first written by k_stats/k_wgemm which run after k_sim).
  short* ve_bf = (short*)Spart;                      // 12544*512 bf16
  short* te_bf = ve_bf + (size_t)12544 * 512;        // 4096*512 bf16

  k_transpose<<<dim3(24, 16, 2), dim3(32, 8), 0, stream>>>(Wv_tok, Wt_tok, Wvt, Wtt);
  k_proj<<<dim3(8, 98), 256, 0, stream>>>(v_tok, Wvt, bv_tok, ve);
  k_proj<<<dim3(8, 32), 256, 0, stream>>>(t_tok, Wtt, bt_tok, te);
  k_normfc<<<3136, 256, 0, stream>>>(ve, wv_fc, bv_fc, vwf, ve_bf, 12544);
  k_normfc<<<1024, 256, 0, stream>>>(te, wt_fc, bt_fc, twf, te_bf, 4096);
  k_softmax<<<128, 256, 0, stream>>>(vwf, twf, tlen);
  k_sim<<<dim3(64, 64), 256, 0, stream>>>(ve_bf, te_bf, vwf, twf, out, gMT, gMV);
  k_stats<<<dim3(8, 13, 4), 256, 0, stream>>>(ve, te, gMT, gMV, vwf, twf, statPart);
  k_statfin<<<4, 512, 0, stream>>>(statPart, stats);
  k_wgemm<<<dim3(4, 8, 16), 256, 0, stream>>>(ve, te, gMT, gMV, vwf, twf, Spart);
  k_assemble<<<512, 256, 0, stream>>>(Spart, stats, lossPart);
  k_loss<<<1, 256, 0, stream>>>(lossPart, out);
}

// Round 3
// 499.677 us; speedup vs baseline: 3.5399x; 1.7096x over previous
//
#include <hip/hip_runtime.h>
#include <cstddef>

#define EDIM 512
#define KDIM 768
#define NB 64
#define NV 196
#define NT 64
#define MROWS_V (NB * NV) /* 12544 */
#define MROWS_T (NB * NT) /* 4096  */

typedef __attribute__((ext_vector_type(8))) short bf16x8;
typedef __attribute__((ext_vector_type(4))) float f32x4;

static __device__ inline unsigned short f2bf(float f) {  // round-to-nearest-even
  unsigned u = __float_as_uint(f);
  unsigned r = (u + 0x7fff + ((u >> 16) & 1)) >> 16;
  return (unsigned short)r;
}
static __device__ inline float bf2f(short s) {
  return __uint_as_float(((unsigned)(unsigned short)s) << 16);
}

// ---------------- fp32 -> bf16 elementwise (8 elems/thread) ----------------
__global__ void k_tobf16(const float* __restrict__ in, short* __restrict__ outp, int n8) {
  int i = blockIdx.x * 256 + threadIdx.x;
  if (i >= n8) return;
  float4 a = *(const float4*)(in + (size_t)i * 8);
  float4 b = *(const float4*)(in + (size_t)i * 8 + 4);
  bf16x8 v;
  v[0] = (short)f2bf(a.x); v[1] = (short)f2bf(a.y);
  v[2] = (short)f2bf(a.z); v[3] = (short)f2bf(a.w);
  v[4] = (short)f2bf(b.x); v[5] = (short)f2bf(b.y);
  v[6] = (short)f2bf(b.z); v[7] = (short)f2bf(b.w);
  *(bf16x8*)(outp + (size_t)i * 8) = v;
}

// ---------------- transpose W [768x512] fp32 -> WT [512x768] bf16 ----------------
__global__ void k_transpose_bf(const float* __restrict__ W0, const float* __restrict__ W1,
                               short* __restrict__ T0, short* __restrict__ T1) {
  __shared__ float tile[32][33];
  const float* W = blockIdx.z ? W1 : W0;
  short*       T = blockIdx.z ? T1 : T0;
  int k0 = blockIdx.x * 32;
  int n0 = blockIdx.y * 32;
  int tx = threadIdx.x, ty = threadIdx.y;
  for (int i = ty; i < 32; i += 8)
    tile[i][tx] = W[(size_t)(k0 + i) * EDIM + n0 + tx];
  __syncthreads();
  for (int i = ty; i < 32; i += 8)
    T[(size_t)(n0 + i) * KDIM + k0 + tx] = (short)f2bf(tile[tx][i]);
}

// ---------- MFMA projection: C[r,n] = sum_k X[r,k]*WT[n,k] + bias[n] (fp32 out) ----
// 128x64 tile, BK=32, 4 waves (wave w -> cols w*16..), same frag scheme as k_sim.
__global__ __launch_bounds__(256, 2) void k_proj_mfma(
    const short* __restrict__ Xbf, const short* __restrict__ WT,
    const float* __restrict__ bias, float* __restrict__ C) {
  __shared__ short As[128 * 40];   // 80 B rows: 32 bf16 + pad (conflict-free)
  __shared__ short Bs[64 * 40];
  int n0 = blockIdx.x * 64;
  int r0 = blockIdx.y * 128;
  int tid = threadIdx.x;
  int w = tid >> 6, lane = tid & 63, lg = lane >> 4, li = lane & 15;
  f32x4 acc[8];
#pragma unroll
  for (int r = 0; r < 8; ++r) acc[r] = (f32x4){0.f, 0.f, 0.f, 0.f};
  for (int kc = 0; kc < KDIM / 32; ++kc) {
    int k0 = kc << 5;
    __syncthreads();
    for (int u = tid; u < 512; u += 256) {   // A: 128 rows x 4 segs
      int r = u >> 2, seg = (u & 3) << 3;
      *(bf16x8*)(As + r * 40 + seg) =
          *(const bf16x8*)(Xbf + (size_t)(r0 + r) * KDIM + k0 + seg);
    }
    {   // B: 64 rows x 4 segs = 256 units
      int t = tid >> 2, seg = (tid & 3) << 3;
      *(bf16x8*)(Bs + t * 40 + seg) =
          *(const bf16x8*)(WT + (size_t)(n0 + t) * KDIM + k0 + seg);
    }
    __syncthreads();
    bf16x8 bfrag = *(const bf16x8*)(Bs + (w * 16 + li) * 40 + lg * 8);
#pragma unroll
    for (int r = 0; r < 8; ++r) {
      bf16x8 afrag = *(const bf16x8*)(As + (r * 16 + li) * 40 + lg * 8);
      acc[r] = __builtin_amdgcn_mfma_f32_16x16x32_bf16(afrag, bfrag, acc[r], 0, 0, 0);
    }
  }
  int n = n0 + w * 16 + li;
  float bb = bias[n];
#pragma unroll
  for (int r = 0; r < 8; ++r)
#pragma unroll
    for (int reg = 0; reg < 4; ++reg)
      C[(size_t)(r0 + r * 16 + lg * 4 + reg) * EDIM + n] = acc[r][reg] + bb;
}

// ------- per-row: fc scalar (pre-norm) + l2 normalize -> bf16 copy only -------
__global__ void k_normfc(const float* __restrict__ M, const float* __restrict__ fcw,
                         const float* __restrict__ fcb, float* __restrict__ wout,
                         short* __restrict__ Mbf, int nrows) {
  int row = blockIdx.x * 4 + (threadIdx.x >> 6);
  int lane = threadIdx.x & 63;
  if (row >= nrows) return;
  const float* p = M + (size_t)row * EDIM;
  float4 a0 = *(const float4*)(p + lane * 8);
  float4 a1 = *(const float4*)(p + lane * 8 + 4);
  float4 w0 = *(const float4*)(fcw + lane * 8);
  float4 w1 = *(const float4*)(fcw + lane * 8 + 4);
  float dot = a0.x * w0.x + a0.y * w0.y + a0.z * w0.z + a0.w * w0.w +
              a1.x * w1.x + a1.y * w1.y + a1.z * w1.z + a1.w * w1.w;
  float ss = a0.x * a0.x + a0.y * a0.y + a0.z * a0.z + a0.w * a0.w +
             a1.x * a1.x + a1.y * a1.y + a1.z * a1.z + a1.w * a1.w;
  for (int s = 1; s < 64; s <<= 1) {
    dot += __shfl_xor(dot, s);
    ss += __shfl_xor(ss, s);
  }
  float inv = 1.0f / fmaxf(sqrtf(ss), 1e-12f);
  bf16x8 bv;
  bv[0] = (short)f2bf(a0.x * inv); bv[1] = (short)f2bf(a0.y * inv);
  bv[2] = (short)f2bf(a0.z * inv); bv[3] = (short)f2bf(a0.w * inv);
  bv[4] = (short)f2bf(a1.x * inv); bv[5] = (short)f2bf(a1.y * inv);
  bv[6] = (short)f2bf(a1.z * inv); bv[7] = (short)f2bf(a1.w * inv);
  *(bf16x8*)(Mbf + (size_t)row * EDIM + lane * 8) = bv;
  if (lane == 0) wout[row] = dot + fcb[0];
}

// ---------------- softmax: blocks 0..63 vw rows (196), 64..127 tw rows (64, masked) ----
__global__ void k_softmax(float* __restrict__ vwf, float* __restrict__ twf,
                          const int* __restrict__ tlen) {
  __shared__ float red[8];
  int tid = threadIdx.x;
  if (blockIdx.x < 64) {
    int b = blockIdx.x;
    float x = (tid < NV) ? vwf[b * NV + tid] : -1e30f;
    float m = x;
    for (int s = 1; s < 64; s <<= 1) m = fmaxf(m, __shfl_xor(m, s));
    if ((tid & 63) == 0) red[tid >> 6] = m;
    __syncthreads();
    m = fmaxf(fmaxf(red[0], red[1]), fmaxf(red[2], red[3]));
    float e = (tid < NV) ? expf(x - m) : 0.0f;
    float s = e;
    for (int st = 1; st < 64; st <<= 1) s += __shfl_xor(s, st);
    if ((tid & 63) == 0) red[4 + (tid >> 6)] = s;
    __syncthreads();
    s = red[4] + red[5] + red[6] + red[7];
    if (tid < NV) vwf[b * NV + tid] = e / s;
  } else {
    int b = blockIdx.x - 64;
    if (tid < 64) {
      int len = tlen[b];
      float x = twf[b * NT + tid];
      bool valid = tid < len;
      float xv = valid ? x : -1e30f;
      float m = xv;
      for (int s = 1; s < 64; s <<= 1) m = fmaxf(m, __shfl_xor(m, s));
      float e = valid ? expf(x - m) : 0.0f;
      float s = e;
      for (int st = 1; st < 64; st <<= 1) s += __shfl_xor(s, st);
      twf[b * NT + tid] = e / s;
    }
  }
}

// ---------------- MFMA sim kernel: one block (4 waves) per (b,q) --------------------
__global__ __launch_bounds__(256, 2) void k_sim(
    const short* __restrict__ ve_bf, const short* __restrict__ te_bf,
    const float* __restrict__ vwf, const float* __restrict__ twf,
    float* __restrict__ out, int* __restrict__ gMT, int* __restrict__ gMV) {
  __shared__ short As[208 * 40];
  __shared__ short Bs[64 * 40];
  __shared__ float rowv[196 * 4];
  __shared__ int   rowi[196 * 4];
  __shared__ float colpart[64];
  __shared__ float redp[4];
  int q = blockIdx.x, b = blockIdx.y;
  int tid = threadIdx.x;
  int w = tid >> 6, lane = tid & 63;
  int lg = lane >> 4, li = lane & 15;
  const short* Abf = ve_bf + (size_t)b * NV * EDIM;
  const short* Bbf = te_bf + (size_t)q * NT * EDIM;
  f32x4 acc[13];
#pragma unroll
  for (int r = 0; r < 13; ++r) acc[r] = (f32x4){0.f, 0.f, 0.f, 0.f};

  for (int kc = 0; kc < 16; ++kc) {
    int k0 = kc << 5;
    __syncthreads();
    {
      int t = tid >> 2, seg = tid & 3;
      *(int4*)(Bs + t * 40 + seg * 8) = *(const int4*)(Bbf + (size_t)t * EDIM + k0 + seg * 8);
    }
    for (int u = tid; u < NV * 4; u += 256) {
      int v = u >> 2, seg = u & 3;
      *(int4*)(As + v * 40 + seg * 8) = *(const int4*)(Abf + (size_t)v * EDIM + k0 + seg * 8);
    }
    __syncthreads();
    bf16x8 bfrag = *(const bf16x8*)(Bs + (w * 16 + li) * 40 + lg * 8);
#pragma unroll
    for (int r = 0; r < 13; ++r) {
      bf16x8 afrag = *(const bf16x8*)(As + (r * 16 + li) * 40 + lg * 8);
      acc[r] = __builtin_amdgcn_mfma_f32_16x16x32_bf16(afrag, bfrag, acc[r], 0, 0, 0);
    }
  }

  bool diag = (b == q);
#pragma unroll
  for (int r = 0; r < 13; ++r) {
#pragma unroll
    for (int reg = 0; reg < 4; ++reg) {
      int v = r * 16 + lg * 4 + reg;
      float m = acc[r][reg];
      int ti = w * 16 + li;
      for (int d = 1; d < 16; d <<= 1) {
        float om = __shfl_xor(m, d);
        int oi = __shfl_xor(ti, d);
        if (om > m || (om == m && oi < ti)) { m = om; ti = oi; }
      }
      if (li == 0 && v < NV) { rowv[v * 4 + w] = m; rowi[v * 4 + w] = ti; }
    }
  }
  {
    float cm = -__builtin_huge_valf();
    int cv = 0;
#pragma unroll
    for (int r = 0; r < 13; ++r) {
#pragma unroll
      for (int reg = 0; reg < 4; ++reg) {
        int v = r * 16 + lg * 4 + reg;
        float s = (v < NV) ? acc[r][reg] : -__builtin_huge_valf();
        if (s > cm) { cm = s; cv = v; }
      }
    }
    for (int d = 16; d < 64; d <<= 1) {
      float om = __shfl_xor(cm, d);
      int ov = __shfl_xor(cv, d);
      if (om > cm || (om == cm && ov < cv)) { cm = om; cv = ov; }
    }
    int t = w * 16 + li;
    if (lg == 0) {
      if (diag) gMV[b * NT + t] = b * NV + cv;
      colpart[t] = twf[q * NT + t] * cm;
    }
  }
  __syncthreads();
  float ip = 0.f;
  if (tid < NV) {
    float m = rowv[tid * 4];
    int ti = rowi[tid * 4];
#pragma unroll
    for (int w2 = 1; w2 < 4; ++w2) {
      float om = rowv[tid * 4 + w2];
      int oi = rowi[tid * 4 + w2];
      if (om > m || (om == m && oi < ti)) { m = om; ti = oi; }
    }
    if (diag) gMT[b * NV + tid] = b * NT + ti;
    ip = vwf[b * NV + tid] * m;
  }
  for (int d = 1; d < 64; d <<= 1) ip += __shfl_xor(ip, d);
  if (lane == 0) redp[w] = ip;
  if (w == 1) {
    float p = colpart[lane];
    for (int d = 1; d < 64; d <<= 1) p += __shfl_xor(p, d);
    if (lane == 0) out[4096 + b * 64 + q] = p;
  }
  __syncthreads();
  if (tid == 0) out[b * 64 + q] = redp[0] + redp[1] + redp[2] + redp[3];
}

// ---------------- column stats from bf16 (sum, sumsq, weighted sum) ------
__global__ void k_stats(const short* __restrict__ ve_bf, const short* __restrict__ te_bf,
                        const int* __restrict__ gMT, const int* __restrict__ gMV,
                        const float* __restrict__ vwf, const float* __restrict__ twf,
                        float* __restrict__ statPart) {
  int stripe = blockIdx.x, chunk = blockIdx.y, m = blockIdx.z;
  int R = (m < 2) ? MROWS_T : MROWS_V;
  int nchunk = (R + 1023) >> 10;
  if (chunk >= nchunk) return;
  const short* M; const int* g; const float* w;
  if (m == 0)      { M = te_bf; g = 0;   w = twf; }
  else if (m == 1) { M = ve_bf; g = gMV; w = twf; }
  else if (m == 2) { M = ve_bf; g = 0;   w = vwf; }
  else             { M = te_bf; g = gMT; w = vwf; }
  int col = stripe * 64 + (threadIdx.x & 63);
  int rg = threadIdx.x >> 6;
  int r0 = chunk << 10;
  int r1 = min(r0 + 1024, R);
  float s = 0, ss = 0, sw = 0;
  for (int r = r0 + rg; r < r1; r += 4) {
    int row = g ? g[r] : r;
    float x = bf2f(M[(size_t)row * EDIM + col]);
    s += x; ss += x * x; sw += w[r] * x;
  }
  __shared__ float red[3][256];
  red[0][threadIdx.x] = s; red[1][threadIdx.x] = ss; red[2][threadIdx.x] = sw;
  __syncthreads();
  if (threadIdx.x < 64) {
    int c = threadIdx.x;
    float S  = red[0][c] + red[0][c + 64] + red[0][c + 128] + red[0][c + 192];
    float SS = red[1][c] + red[1][c + 64] + red[1][c + 128] + red[1][c + 192];
    float SW = red[2][c] + red[2][c + 64] + red[2][c + 128] + red[2][c + 192];
    size_t idx = ((size_t)(m * 13 + chunk) * 512 + stripe * 64 + c) * 3;
    statPart[idx] = S; statPart[idx + 1] = SS; statPart[idx + 2] = SW;
  }
}

__global__ void k_statfin(const float* __restrict__ statPart, float* __restrict__ stats) {
  int m = blockIdx.x, c = threadIdx.x;
  int R = (m < 2) ? MROWS_T : MROWS_V;
  int nchunk = (R + 1023) >> 10;
  float s = 0, ss = 0, sw = 0;
  for (int ch = 0; ch < nchunk; ch++) {
    size_t idx = ((size_t)(m * 13 + ch) * 512 + c) * 3;
    s += statPart[idx]; ss += statPart[idx + 1]; sw += statPart[idx + 2];
  }
  float mean = s / R;
  float var = (ss - s * mean) / (R - 1);  // ddof=1
  float rstd = 1.0f / sqrtf(var);
  stats[(m * 3 + 0) * 512 + c] = mean;
  stats[(m * 3 + 1) * 512 + c] = rstd;
  stats[(m * 3 + 2) * 512 + c] = sw;
}

// ------- transpose-materialize a-contiguous bf16 operands (w and gathers folded) ----
// z: 0 tTw[c][a]=tw[a]*te[a][c], 1 mvT[d][a]=ve[gMV[a]][d],
//    2 vTw[c][a]=vw[a]*ve[a][c], 3 mtT[d][a]=te[gMT[a]][d]
__global__ void k_materialize(const short* __restrict__ ve_bf, const short* __restrict__ te_bf,
                              const int* __restrict__ gMT, const int* __restrict__ gMV,
                              const float* __restrict__ vwf, const float* __restrict__ twf,
                              short* __restrict__ tTw, short* __restrict__ mvT,
                              short* __restrict__ vTw, short* __restrict__ mtT) {
  int z = blockIdx.z;
  int at = blockIdx.x, ct = blockIdx.y;
  int K = (z == 2 || z == 3) ? MROWS_V : MROWS_T;
  if (at * 64 >= K) return;
  const short* src; const int* g = 0; const float* w = 0; short* dst;
  if (z == 0)      { src = te_bf; w = twf; dst = tTw; }
  else if (z == 1) { src = ve_bf; g = gMV; dst = mvT; }
  else if (z == 2) { src = ve_bf; w = vwf; dst = vTw; }
  else             { src = te_bf; g = gMT; dst = mtT; }
  __shared__ float tile[64][67];
  int tid = threadIdx.x;
  for (int u = tid; u < 512; u += 256) {
    int a = u >> 3, cseg = (u & 7) << 3;
    int ga = at * 64 + a;
    int row = g ? g[ga] : ga;
    bf16x8 vv = *(const bf16x8*)(src + (size_t)row * EDIM + ct * 64 + cseg);
    float wa = w ? w[ga] : 1.0f;
#pragma unroll
    for (int j = 0; j < 8; j++) tile[a][cseg + j] = wa * bf2f(vv[j]);
  }
  __syncthreads();
  for (int u = tid; u < 512; u += 256) {
    int c = u >> 3, aseg = (u & 7) << 3;
    bf16x8 ov;
#pragma unroll
    for (int j = 0; j < 8; j++) ov[j] = (short)f2bf(tile[aseg + j][c]);
    *(bf16x8*)(dst + (size_t)(ct * 64 + c) * K + at * 64 + aseg) = ov;
  }
}

// ------- MFMA weighted GEMM: Spart[z][c][d] = sum_a AT[c][a]*BT[d][a] (split-K 4) ----
__global__ __launch_bounds__(256, 2) void k_wgemm2(
    const short* __restrict__ tTw, const short* __restrict__ mvT,
    const short* __restrict__ vTw, const short* __restrict__ mtT,
    float* __restrict__ Spart) {
  __shared__ short As[128 * 40];
  __shared__ short Bs[64 * 40];
  int c0 = blockIdx.x * 128, d0 = blockIdx.y * 64;
  int z = blockIdx.z;
  int which = z >> 2, slice = z & 3;
  const short* A = which ? vTw : tTw;
  const short* B = which ? mtT : mvT;
  int K = which ? MROWS_V : MROWS_T;
  int nch = (K >> 2) >> 5;             // 98 or 32 chunks of 32
  int a0 = slice * (K >> 2);
  int tid = threadIdx.x;
  int w = tid >> 6, lane = tid & 63, lg = lane >> 4, li = lane & 15;
  f32x4 acc[8];
#pragma unroll
  for (int r = 0; r < 8; ++r) acc[r] = (f32x4){0.f, 0.f, 0.f, 0.f};
  for (int ch = 0; ch < nch; ++ch) {
    int ak = a0 + (ch << 5);
    __syncthreads();
    for (int u = tid; u < 512; u += 256) {
      int r = u >> 2, seg = (u & 3) << 3;
      *(bf16x8*)(As + r * 40 + seg) = *(const bf16x8*)(A + (size_t)(c0 + r) * K + ak + seg);
    }
    {
      int t = tid >> 2, seg = (tid & 3) << 3;
      *(bf16x8*)(Bs + t * 40 + seg) = *(const bf16x8*)(B + (size_t)(d0 + t) * K + ak + seg);
    }
    __syncthreads();
    bf16x8 bfrag = *(const bf16x8*)(Bs + (w * 16 + li) * 40 + lg * 8);
#pragma unroll
    for (int r = 0; r < 8; ++r) {
      bf16x8 afrag = *(const bf16x8*)(As + (r * 16 + li) * 40 + lg * 8);
      acc[r] = __builtin_amdgcn_mfma_f32_16x16x32_bf16(afrag, bfrag, acc[r], 0, 0, 0);
    }
  }
  float* outp = Spart + (size_t)z * 512 * 512;
  int d = d0 + w * 16 + li;
#pragma unroll
  for (int r = 0; r < 8; ++r)
#pragma unroll
    for (int reg = 0; reg < 4; ++reg)
      outp[(size_t)(c0 + r * 16 + lg * 4 + reg) * 512 + d] = acc[r][reg];
}

// ---------------- assemble c = (c1+c2)/2 from closed form; loss partials ----------
__global__ void k_assemble(const float* __restrict__ Spart, const float* __restrict__ stats,
                           float* __restrict__ lossPart) {
  int c = blockIdx.x, tid = threadIdx.x;
  float muT = stats[0 * 512 + c], rsT = stats[1 * 512 + c], swT = stats[2 * 512 + c];
  float muV = stats[6 * 512 + c], rsV = stats[7 * 512 + c], swV = stats[8 * 512 + c];
  const float W = 64.0f, invB = 1.0f / 64.0f;
  float on = 0, off = 0;
  for (int d = tid; d < 512; d += 256) {
    float s1 = 0, s2 = 0;
    for (int sl = 0; sl < 4; sl++) {
      s1 += Spart[((size_t)sl * 512 + c) * 512 + d];
      s2 += Spart[((size_t)(4 + sl) * 512 + c) * 512 + d];
    }
    float muMV = stats[3 * 512 + d], rsMV = stats[4 * 512 + d], swMV = stats[5 * 512 + d];
    float muMT = stats[9 * 512 + d], rsMT = stats[10 * 512 + d], swMT = stats[11 * 512 + d];
    float c1 = (s1 - muT * swMV - muMV * swT + muT * muMV * W) * rsT * rsMV * invB;
    float c2 = (s2 - muV * swMT - muMT * swV + muV * muMT * W) * rsV * rsMT * invB;
    float cc = 0.5f * (c1 + c2);
    if (d == c) { float dd = cc - 1.0f; on += dd * dd; }
    else off += cc * cc;
  }
  __shared__ float r1[4], r2[4];
  for (int s = 1; s < 64; s <<= 1) { on += __shfl_xor(on, s); off += __shfl_xor(off, s); }
  if ((tid & 63) == 0) { r1[tid >> 6] = on; r2[tid >> 6] = off; }
  __syncthreads();
  if (tid == 0) {
    lossPart[c * 2] = r1[0] + r1[1] + r1[2] + r1[3];
    lossPart[c * 2 + 1] = r2[0] + r2[1] + r2[2] + r2[3];
  }
}

__global__ void k_loss(const float* __restrict__ lossPart, float* __restrict__ out) {
  int tid = threadIdx.x;
  float on = 0, off = 0;
  for (int i = tid; i < 512; i += 256) { on += lossPart[2 * i]; off += lossPart[2 * i + 1]; }
  __shared__ float r1[4], r2[4];
  for (int s = 1; s < 64; s <<= 1) { on += __shfl_xor(on, s); off += __shfl_xor(off, s); }
  if ((tid & 63) == 0) { r1[tid >> 6] = on; r2[tid >> 6] = off; }
  __syncthreads();
  if (tid == 0)
    out[8192] = 0.1f * ((r1[0] + r1[1] + r1[2] + r1[3]) +
                        0.06f * (r2[0] + r2[1] + r2[2] + r2[3]));
}

extern "C" void kernel_launch(void* const* d_in, const int* in_sizes, int n_in,
                              void* d_out, int out_size, void* d_ws, size_t ws_size,
                              hipStream_t stream) {
  (void)in_sizes; (void)n_in; (void)out_size; (void)ws_size;
  const float* v_tok  = (const float*)d_in[1];
  const float* t_tok  = (const float*)d_in[3];
  const float* Wv_tok = (const float*)d_in[8];
  const float* Wt_tok = (const float*)d_in[10];
  const float* bv_tok = (const float*)d_in[9];
  const float* bt_tok = (const float*)d_in[11];
  const float* wv_fc  = (const float*)d_in[12];
  const float* bv_fc  = (const float*)d_in[13];
  const float* wt_fc  = (const float*)d_in[14];
  const float* bt_fc  = (const float*)d_in[15];
  const int*   tlen   = (const int*)d_in[16];
  float* out = (float*)d_out;

  char* wsb = (char*)d_ws;
  // --- R0 (27,131,904 B): phase 1 {v_tok_bf, t_tok_bf, WvT, WtT};
  //     after proj: {ve_bf, te_bf, Spart} (lifetime-disjoint, stream-ordered)
  short* v_tok_bf = (short*)wsb;                       // 9,633,792 sh
  short* t_tok_bf = v_tok_bf + (size_t)9633792;        // 3,145,728 sh
  short* WvT      = t_tok_bf + (size_t)3145728;        //   393,216 sh
  short* WtT      = WvT + (size_t)393216;              //   393,216 sh
  short* ve_bf    = (short*)wsb;                       // 6,422,528 sh (alias v_tok_bf)
  short* te_bf    = ve_bf + (size_t)6422528;           // 2,097,152 sh
  float* Spart    = (float*)(wsb + 17039360);          // 8*512*512 f (alias tail)
  // --- R1 (34,078,720 B): phase 1 {ve, te fp32}; after normfc: transposed operands
  float* ve  = (float*)(wsb + 27131904);               // 6,422,528 f
  float* te  = ve + (size_t)6422528;                   // 2,097,152 f
  short* tTw = (short*)(wsb + 27131904);               // 512*4096  (alias)
  short* mvT = tTw + (size_t)2097152;                  // 512*4096
  short* vTw = mvT + (size_t)2097152;                  // 512*12544
  short* mtT = vTw + (size_t)6422528;                  // 512*12544
  // --- R2 smalls
  float* vwf = (float*)(wsb + 61210624);               // 12544
  float* twf = vwf + 12544;                            // 4096
  int* gMT = (int*)(twf + 4096);                       // 12544
  int* gMV = gMT + 12544;                              // 4096
  float* statPart = (float*)(gMV + 4096);              // 4*13*512*3
  float* stats = statPart + 79872;                     // 12*512
  float* lossPart = stats + 6144;                      // 1024

  k_tobf16<<<4704, 256, 0, stream>>>(v_tok, v_tok_bf, 1204224);
  k_tobf16<<<1536, 256, 0, stream>>>(t_tok, t_tok_bf, 393216);
  k_transpose_bf<<<dim3(24, 16, 2), dim3(32, 8), 0, stream>>>(Wv_tok, Wt_tok, WvT, WtT);
  k_proj_mfma<<<dim3(8, 98), 256, 0, stream>>>(v_tok_bf, WvT, bv_tok, ve);
  k_proj_mfma<<<dim3(8, 32), 256, 0, stream>>>(t_tok_bf, WtT, bt_tok, te);
  k_normfc<<<3136, 256, 0, stream>>>(ve, wv_fc, bv_fc, vwf, ve_bf, 12544);
  k_normfc<<<1024, 256, 0, stream>>>(te, wt_fc, bt_fc, twf, te_bf, 4096);
  k_softmax<<<128, 256, 0, stream>>>(vwf, twf, tlen);
  k_sim<<<dim3(64, 64), 256, 0, stream>>>(ve_bf, te_bf, vwf, twf, out, gMT, gMV);
  k_stats<<<dim3(8, 13, 4), 256, 0, stream>>>(ve_bf, te_bf, gMT, gMV, vwf, twf, statPart);
  k_statfin<<<4, 512, 0, stream>>>(statPart, stats);
  k_materialize<<<dim3(196, 8, 4), 256, 0, stream>>>(ve_bf, te_bf, gMT, gMV, vwf, twf,
                                                     tTw, mvT, vTw, mtT);
  k_wgemm2<<<dim3(4, 8, 8), 256, 0, stream>>>(tTw, mvT, vTw, mtT, Spart);
  k_assemble<<<512, 256, 0, stream>>>(Spart, stats, lossPart);
  k_loss<<<1, 256, 0, stream>>>(lossPart, out);
}

// Round 4
// 392.770 us; speedup vs baseline: 4.5034x; 1.2722x over previous
//
#include <hip/hip_runtime.h>
#include <cstddef>

#define EDIM 512
#define KDIM 768
#define NB 64
#define NV 196
#define NT 64
#define MROWS_V (NB * NV) /* 12544 */
#define MROWS_T (NB * NT) /* 4096  */

typedef __attribute__((ext_vector_type(8))) short bf16x8;
typedef __attribute__((ext_vector_type(4))) float f32x4;

static __device__ inline unsigned short f2bf(float f) {  // round-to-nearest-even
  unsigned u = __float_as_uint(f);
  unsigned r = (u + 0x7fff + ((u >> 16) & 1)) >> 16;
  return (unsigned short)r;
}
static __device__ inline float bf2f(short s) {
  return __uint_as_float(((unsigned)(unsigned short)s) << 16);
}

// ---------------- fp32 -> bf16 elementwise (8 elems/thread) ----------------
__global__ void k_tobf16(const float* __restrict__ in, short* __restrict__ outp, int n8) {
  int i = blockIdx.x * 256 + threadIdx.x;
  if (i >= n8) return;
  float4 a = *(const float4*)(in + (size_t)i * 8);
  float4 b = *(const float4*)(in + (size_t)i * 8 + 4);
  bf16x8 v;
  v[0] = (short)f2bf(a.x); v[1] = (short)f2bf(a.y);
  v[2] = (short)f2bf(a.z); v[3] = (short)f2bf(a.w);
  v[4] = (short)f2bf(b.x); v[5] = (short)f2bf(b.y);
  v[6] = (short)f2bf(b.z); v[7] = (short)f2bf(b.w);
  *(bf16x8*)(outp + (size_t)i * 8) = v;
}

// ---------------- transpose W [768x512] fp32 -> WT [512x768] bf16 ----------------
__global__ void k_transpose_bf(const float* __restrict__ W0, const float* __restrict__ W1,
                               short* __restrict__ T0, short* __restrict__ T1) {
  __shared__ float tile[32][33];
  const float* W = blockIdx.z ? W1 : W0;
  short*       T = blockIdx.z ? T1 : T0;
  int k0 = blockIdx.x * 32;
  int n0 = blockIdx.y * 32;
  int tx = threadIdx.x, ty = threadIdx.y;
  for (int i = ty; i < 32; i += 8)
    tile[i][tx] = W[(size_t)(k0 + i) * EDIM + n0 + tx];
  __syncthreads();
  for (int i = ty; i < 32; i += 8)
    T[(size_t)(n0 + i) * KDIM + k0 + tx] = (short)f2bf(tile[tx][i]);
}

// ---------- MFMA projection: C[r,n] = sum_k X[r,k]*WT[n,k] + bias[n] (fp32 out) ----
// 128x64 tile, BK=32; wave w owns row-tiles {2w,2w+1} x all 4 col-tiles.
__global__ __launch_bounds__(256, 4) void k_proj_mfma(
    const short* __restrict__ Xbf, const short* __restrict__ WT,
    const float* __restrict__ bias, float* __restrict__ C) {
  __shared__ short As[128 * 44];   // 88 B stride: <=2-way banks (free)
  __shared__ short Bs[64 * 44];
  int n0 = blockIdx.x * 64;
  int r0 = blockIdx.y * 128;
  int tid = threadIdx.x;
  int w = tid >> 6, lane = tid & 63, lg = lane >> 4, li = lane & 15;
  f32x4 acc[2][4];
#pragma unroll
  for (int i = 0; i < 2; ++i)
#pragma unroll
    for (int j = 0; j < 4; ++j) acc[i][j] = (f32x4){0.f, 0.f, 0.f, 0.f};
  for (int kc = 0; kc < KDIM / 32; ++kc) {
    int k0 = kc << 5;
    __syncthreads();
#pragma unroll
    for (int uu = 0; uu < 2; ++uu) {   // A: 128 rows x 4 segs
      int u = tid + uu * 256;
      int r = u >> 2, seg = (u & 3) << 3;
      *(bf16x8*)(As + r * 44 + seg) =
          *(const bf16x8*)(Xbf + (size_t)(r0 + r) * KDIM + k0 + seg);
    }
    {   // B: 64 rows x 4 segs
      int t = tid >> 2, seg = (tid & 3) << 3;
      *(bf16x8*)(Bs + t * 44 + seg) =
          *(const bf16x8*)(WT + (size_t)(n0 + t) * KDIM + k0 + seg);
    }
    __syncthreads();
    bf16x8 bfr[4];
#pragma unroll
    for (int j = 0; j < 4; ++j)
      bfr[j] = *(const bf16x8*)(Bs + (j * 16 + li) * 44 + lg * 8);
#pragma unroll
    for (int i = 0; i < 2; ++i) {
      bf16x8 afr = *(const bf16x8*)(As + ((w * 2 + i) * 16 + li) * 44 + lg * 8);
#pragma unroll
      for (int j = 0; j < 4; ++j)
        acc[i][j] = __builtin_amdgcn_mfma_f32_16x16x32_bf16(afr, bfr[j], acc[i][j], 0, 0, 0);
    }
  }
#pragma unroll
  for (int j = 0; j < 4; ++j) {
    int n = n0 + j * 16 + li;
    float bb = bias[n];
#pragma unroll
    for (int i = 0; i < 2; ++i)
#pragma unroll
      for (int reg = 0; reg < 4; ++reg)
        C[(size_t)(r0 + (w * 2 + i) * 16 + lg * 4 + reg) * EDIM + n] = acc[i][j][reg] + bb;
  }
}

// ------- per-row: fc scalar (pre-norm) + l2 normalize -> bf16 copy only -------
__global__ void k_normfc(const float* __restrict__ M, const float* __restrict__ fcw,
                         const float* __restrict__ fcb, float* __restrict__ wout,
                         short* __restrict__ Mbf, int nrows) {
  int row = blockIdx.x * 4 + (threadIdx.x >> 6);
  int lane = threadIdx.x & 63;
  if (row >= nrows) return;
  const float* p = M + (size_t)row * EDIM;
  float4 a0 = *(const float4*)(p + lane * 8);
  float4 a1 = *(const float4*)(p + lane * 8 + 4);
  float4 w0 = *(const float4*)(fcw + lane * 8);
  float4 w1 = *(const float4*)(fcw + lane * 8 + 4);
  float dot = a0.x * w0.x + a0.y * w0.y + a0.z * w0.z + a0.w * w0.w +
              a1.x * w1.x + a1.y * w1.y + a1.z * w1.z + a1.w * w1.w;
  float ss = a0.x * a0.x + a0.y * a0.y + a0.z * a0.z + a0.w * a0.w +
             a1.x * a1.x + a1.y * a1.y + a1.z * a1.z + a1.w * a1.w;
  for (int s = 1; s < 64; s <<= 1) {
    dot += __shfl_xor(dot, s);
    ss += __shfl_xor(ss, s);
  }
  float inv = 1.0f / fmaxf(sqrtf(ss), 1e-12f);
  bf16x8 bv;
  bv[0] = (short)f2bf(a0.x * inv); bv[1] = (short)f2bf(a0.y * inv);
  bv[2] = (short)f2bf(a0.z * inv); bv[3] = (short)f2bf(a0.w * inv);
  bv[4] = (short)f2bf(a1.x * inv); bv[5] = (short)f2bf(a1.y * inv);
  bv[6] = (short)f2bf(a1.z * inv); bv[7] = (short)f2bf(a1.w * inv);
  *(bf16x8*)(Mbf + (size_t)row * EDIM + lane * 8) = bv;
  if (lane == 0) wout[row] = dot + fcb[0];
}

// ---------------- softmax: blocks 0..63 vw rows (196), 64..127 tw rows (64, masked) ----
__global__ void k_softmax(float* __restrict__ vwf, float* __restrict__ twf,
                          const int* __restrict__ tlen) {
  __shared__ float red[8];
  int tid = threadIdx.x;
  if (blockIdx.x < 64) {
    int b = blockIdx.x;
    float x = (tid < NV) ? vwf[b * NV + tid] : -1e30f;
    float m = x;
    for (int s = 1; s < 64; s <<= 1) m = fmaxf(m, __shfl_xor(m, s));
    if ((tid & 63) == 0) red[tid >> 6] = m;
    __syncthreads();
    m = fmaxf(fmaxf(red[0], red[1]), fmaxf(red[2], red[3]));
    float e = (tid < NV) ? expf(x - m) : 0.0f;
    float s = e;
    for (int st = 1; st < 64; st <<= 1) s += __shfl_xor(s, st);
    if ((tid & 63) == 0) red[4 + (tid >> 6)] = s;
    __syncthreads();
    s = red[4] + red[5] + red[6] + red[7];
    if (tid < NV) vwf[b * NV + tid] = e / s;
  } else {
    int b = blockIdx.x - 64;
    if (tid < 64) {
      int len = tlen[b];
      float x = twf[b * NT + tid];
      bool valid = tid < len;
      float xv = valid ? x : -1e30f;
      float m = xv;
      for (int s = 1; s < 64; s <<= 1) m = fmaxf(m, __shfl_xor(m, s));
      float e = valid ? expf(x - m) : 0.0f;
      float s = e;
      for (int st = 1; st < 64; st <<= 1) s += __shfl_xor(s, st);
      twf[b * NT + tid] = e / s;
    }
  }
}

// ---------------- MFMA sim kernel: one block (4 waves) per (b,q) --------------------
// Wave w owns row-tiles {4w..4w+3} (rows padded to 256) x ALL 4 col-tiles.
// Per kc: 4 B-frag + 4 A-frag reads -> 16 MFMAs (0.5 reads/MFMA).
__global__ __launch_bounds__(256, 4) void k_sim(
    const short* __restrict__ ve_bf, const short* __restrict__ te_bf,
    const float* __restrict__ vwf, const float* __restrict__ twf,
    float* __restrict__ out, int* __restrict__ gMT, int* __restrict__ gMV) {
  __shared__ short As[256 * 44];   // 88 B stride, <=2-way banks
  __shared__ short Bs[64 * 44];
  __shared__ float colv[4][64];
  __shared__ int   coli[4][64];
  __shared__ float redp[4];
  int q = blockIdx.x, b = blockIdx.y;
  int tid = threadIdx.x;
  int w = tid >> 6, lane = tid & 63, lg = lane >> 4, li = lane & 15;
  const short* Abf = ve_bf + (size_t)b * NV * EDIM;
  const short* Bbf = te_bf + (size_t)q * NT * EDIM;
  f32x4 acc[4][4];
#pragma unroll
  for (int i = 0; i < 4; ++i)
#pragma unroll
    for (int j = 0; j < 4; ++j) acc[i][j] = (f32x4){0.f, 0.f, 0.f, 0.f};

  for (int kc = 0; kc < 16; ++kc) {
    int k0 = kc << 5;
    __syncthreads();
    {   // B: 64 rows x 4 segs = 256 units
      int t = tid >> 2, seg = (tid & 3) << 3;
      *(bf16x8*)(Bs + t * 44 + seg) =
          *(const bf16x8*)(Bbf + (size_t)t * EDIM + k0 + seg);
    }
#pragma unroll
    for (int uu = 0; uu < 4; ++uu) {   // A: 196 real rows x 4 segs (pads stale, masked)
      int u = tid + uu * 256;
      int v = u >> 2, seg = (u & 3) << 3;
      if (v < NV)
        *(bf16x8*)(As + v * 44 + seg) =
            *(const bf16x8*)(Abf + (size_t)v * EDIM + k0 + seg);
    }
    __syncthreads();
    bf16x8 bfr[4];
#pragma unroll
    for (int j = 0; j < 4; ++j)
      bfr[j] = *(const bf16x8*)(Bs + (j * 16 + li) * 44 + lg * 8);
#pragma unroll
    for (int i = 0; i < 4; ++i) {
      bf16x8 afr = *(const bf16x8*)(As + ((w * 4 + i) * 16 + li) * 44 + lg * 8);
#pragma unroll
      for (int j = 0; j < 4; ++j)
        acc[i][j] = __builtin_amdgcn_mfma_f32_16x16x32_bf16(afr, bfr[j], acc[i][j], 0, 0, 0);
    }
  }

  bool diag = (b == q);
  // ---- row (over t) max+argmax: fully wave-local (wave holds all 64 t's of its rows)
  float ip = 0.f;
#pragma unroll
  for (int i = 0; i < 4; ++i) {
#pragma unroll
    for (int reg = 0; reg < 4; ++reg) {
      int v = (w * 4 + i) * 16 + lg * 4 + reg;
      float m = acc[i][0][reg];
      int ti = li;
#pragma unroll
      for (int j = 1; j < 4; ++j) {
        float vv = acc[i][j][reg];
        int t = j * 16 + li;
        if (vv > m) { m = vv; ti = t; }   // j ascending -> first-index kept
      }
      for (int d = 1; d < 16; d <<= 1) {  // within 16-lane lg-group
        float om = __shfl_xor(m, d);
        int oi = __shfl_xor(ti, d);
        if (om > m || (om == m && oi < ti)) { m = om; ti = oi; }
      }
      if (li == 0 && v < NV) {
        ip += vwf[b * NV + v] * m;
        if (diag) gMT[b * NV + v] = b * NT + ti;
      }
    }
  }
  for (int d = 1; d < 64; d <<= 1) ip += __shfl_xor(ip, d);
  if (lane == 0) redp[w] = ip;
  // ---- col (over v) max+argmax: per-lane over regs, cross-lg shfl, cross-wave LDS
  float cm[4]; int cv[4];
#pragma unroll
  for (int j = 0; j < 4; ++j) { cm[j] = -3.0e38f; cv[j] = 0; }
#pragma unroll
  for (int i = 0; i < 4; ++i)
#pragma unroll
    for (int reg = 0; reg < 4; ++reg) {
      int v = (w * 4 + i) * 16 + lg * 4 + reg;
      bool ok = v < NV;
#pragma unroll
      for (int j = 0; j < 4; ++j) {
        float s = ok ? acc[i][j][reg] : -3.0e38f;
        if (s > cm[j]) { cm[j] = s; cv[j] = v; }  // v ascending per lane
      }
    }
#pragma unroll
  for (int j = 0; j < 4; ++j) {
    for (int d = 16; d < 64; d <<= 1) {
      float om = __shfl_xor(cm[j], d);
      int ov = __shfl_xor(cv[j], d);
      if (om > cm[j] || (om == cm[j] && ov < cv[j])) { cm[j] = om; cv[j] = ov; }
    }
    if (lg == 0) { colv[w][j * 16 + li] = cm[j]; coli[w][j * 16 + li] = cv[j]; }
  }
  __syncthreads();
  if (tid < 64) {
    int t = tid;
    float m = colv[0][t];
    int bi = coli[0][t];
#pragma unroll
    for (int w2 = 1; w2 < 4; ++w2) {
      float om = colv[w2][t];
      int ov = coli[w2][t];
      if (om > m || (om == m && ov < bi)) { m = om; bi = ov; }
    }
    if (diag) gMV[b * NT + t] = b * NV + bi;
    float p = twf[q * NT + t] * m;
    for (int d = 1; d < 64; d <<= 1) p += __shfl_xor(p, d);
    if (t == 0) out[4096 + b * 64 + q] = p;
  }
  if (tid == 0) out[b * 64 + q] = redp[0] + redp[1] + redp[2] + redp[3];
}

// ---------------- column stats from bf16 (sum, sumsq, weighted sum) ------
__global__ void k_stats(const short* __restrict__ ve_bf, const short* __restrict__ te_bf,
                        const int* __restrict__ gMT, const int* __restrict__ gMV,
                        const float* __restrict__ vwf, const float* __restrict__ twf,
                        float* __restrict__ statPart) {
  int stripe = blockIdx.x, chunk = blockIdx.y, m = blockIdx.z;
  int R = (m < 2) ? MROWS_T : MROWS_V;
  int nchunk = (R + 1023) >> 10;
  if (chunk >= nchunk) return;
  const short* M; const int* g; const float* w;
  if (m == 0)      { M = te_bf; g = 0;   w = twf; }
  else if (m == 1) { M = ve_bf; g = gMV; w = twf; }
  else if (m == 2) { M = ve_bf; g = 0;   w = vwf; }
  else             { M = te_bf; g = gMT; w = vwf; }
  int col = stripe * 64 + (threadIdx.x & 63);
  int rg = threadIdx.x >> 6;
  int r0 = chunk << 10;
  int r1 = min(r0 + 1024, R);
  float s = 0, ss = 0, sw = 0;
  for (int r = r0 + rg; r < r1; r += 4) {
    int row = g ? g[r] : r;
    float x = bf2f(M[(size_t)row * EDIM + col]);
    s += x; ss += x * x; sw += w[r] * x;
  }
  __shared__ float red[3][256];
  red[0][threadIdx.x] = s; red[1][threadIdx.x] = ss; red[2][threadIdx.x] = sw;
  __syncthreads();
  if (threadIdx.x < 64) {
    int c = threadIdx.x;
    float S  = red[0][c] + red[0][c + 64] + red[0][c + 128] + red[0][c + 192];
    float SS = red[1][c] + red[1][c + 64] + red[1][c + 128] + red[1][c + 192];
    float SW = red[2][c] + red[2][c + 64] + red[2][c + 128] + red[2][c + 192];
    size_t idx = ((size_t)(m * 13 + chunk) * 512 + stripe * 64 + c) * 3;
    statPart[idx] = S; statPart[idx + 1] = SS; statPart[idx + 2] = SW;
  }
}

__global__ void k_statfin(const float* __restrict__ statPart, float* __restrict__ stats) {
  int m = blockIdx.x, c = threadIdx.x;
  int R = (m < 2) ? MROWS_T : MROWS_V;
  int nchunk = (R + 1023) >> 10;
  float s = 0, ss = 0, sw = 0;
  for (int ch = 0; ch < nchunk; ch++) {
    size_t idx = ((size_t)(m * 13 + ch) * 512 + c) * 3;
    s += statPart[idx]; ss += statPart[idx + 1]; sw += statPart[idx + 2];
  }
  float mean = s / R;
  float var = (ss - s * mean) / (R - 1);  // ddof=1
  float rstd = 1.0f / sqrtf(var);
  stats[(m * 3 + 0) * 512 + c] = mean;
  stats[(m * 3 + 1) * 512 + c] = rstd;
  stats[(m * 3 + 2) * 512 + c] = sw;
}

// ------- transpose-materialize a-contiguous bf16 operands (w and gathers folded) ----
__global__ void k_materialize(const short* __restrict__ ve_bf, const short* __restrict__ te_bf,
                              const int* __restrict__ gMT, const int* __restrict__ gMV,
                              const float* __restrict__ vwf, const float* __restrict__ twf,
                              short* __restrict__ tTw, short* __restrict__ mvT,
                              short* __restrict__ vTw, short* __restrict__ mtT) {
  int z = blockIdx.z;
  int at = blockIdx.x, ct = blockIdx.y;
  int K = (z == 2 || z == 3) ? MROWS_V : MROWS_T;
  if (at * 64 >= K) return;
  const short* src; const int* g = 0; const float* w = 0; short* dst;
  if (z == 0)      { src = te_bf; w = twf; dst = tTw; }
  else if (z == 1) { src = ve_bf; g = gMV; dst = mvT; }
  else if (z == 2) { src = ve_bf; w = vwf; dst = vTw; }
  else             { src = te_bf; g = gMT; dst = mtT; }
  __shared__ float tile[64][67];
  int tid = threadIdx.x;
  for (int u = tid; u < 512; u += 256) {
    int a = u >> 3, cseg = (u & 7) << 3;
    int ga = at * 64 + a;
    int row = g ? g[ga] : ga;
    bf16x8 vv = *(const bf16x8*)(src + (size_t)row * EDIM + ct * 64 + cseg);
    float wa = w ? w[ga] : 1.0f;
#pragma unroll
    for (int j = 0; j < 8; j++) tile[a][cseg + j] = wa * bf2f(vv[j]);
  }
  __syncthreads();
  for (int u = tid; u < 512; u += 256) {
    int c = u >> 3, aseg = (u & 7) << 3;
    bf16x8 ov;
#pragma unroll
    for (int j = 0; j < 8; j++) ov[j] = (short)f2bf(tile[aseg + j][c]);
    *(bf16x8*)(dst + (size_t)(ct * 64 + c) * K + at * 64 + aseg) = ov;
  }
}

// ------- MFMA weighted GEMM: Spart[z][c][d] = sum_a AT[c][a]*BT[d][a] (split-K 4) ----
__global__ __launch_bounds__(256, 4) void k_wgemm2(
    const short* __restrict__ tTw, const short* __restrict__ mvT,
    const short* __restrict__ vTw, const short* __restrict__ mtT,
    float* __restrict__ Spart) {
  __shared__ short As[128 * 44];
  __shared__ short Bs[64 * 44];
  int c0 = blockIdx.x * 128, d0 = blockIdx.y * 64;
  int z = blockIdx.z;
  int which = z >> 2, slice = z & 3;
  const short* A = which ? vTw : tTw;
  const short* B = which ? mtT : mvT;
  int K = which ? MROWS_V : MROWS_T;
  int nch = (K >> 2) >> 5;             // 98 or 32 chunks of 32
  int a0 = slice * (K >> 2);
  int tid = threadIdx.x;
  int w = tid >> 6, lane = tid & 63, lg = lane >> 4, li = lane & 15;
  f32x4 acc[2][4];
#pragma unroll
  for (int i = 0; i < 2; ++i)
#pragma unroll
    for (int j = 0; j < 4; ++j) acc[i][j] = (f32x4){0.f, 0.f, 0.f, 0.f};
  for (int ch = 0; ch < nch; ++ch) {
    int ak = a0 + (ch << 5);
    __syncthreads();
#pragma unroll
    for (int uu = 0; uu < 2; ++uu) {
      int u = tid + uu * 256;
      int r = u >> 2, seg = (u & 3) << 3;
      *(bf16x8*)(As + r * 44 + seg) = *(const bf16x8*)(A + (size_t)(c0 + r) * K + ak + seg);
    }
    {
      int t = tid >> 2, seg = (tid & 3) << 3;
      *(bf16x8*)(Bs + t * 44 + seg) = *(const bf16x8*)(B + (size_t)(d0 + t) * K + ak + seg);
    }
    __syncthreads();
    bf16x8 bfr[4];
#pragma unroll
    for (int j = 0; j < 4; ++j)
      bfr[j] = *(const bf16x8*)(Bs + (j * 16 + li) * 44 + lg * 8);
#pragma unroll
    for (int i = 0; i < 2; ++i) {
      bf16x8 afr = *(const bf16x8*)(As + ((w * 2 + i) * 16 + li) * 44 + lg * 8);
#pragma unroll
      for (int j = 0; j < 4; ++j)
        acc[i][j] = __builtin_amdgcn_mfma_f32_16x16x32_bf16(afr, bfr[j], acc[i][j], 0, 0, 0);
    }
  }
  float* outp = Spart + (size_t)z * 512 * 512;
#pragma unroll
  for (int j = 0; j < 4; ++j) {
    int d = d0 + j * 16 + li;
#pragma unroll
    for (int i = 0; i < 2; ++i)
#pragma unroll
      for (int reg = 0; reg < 4; ++reg)
        outp[(size_t)(c0 + (w * 2 + i) * 16 + lg * 4 + reg) * 512 + d] = acc[i][j][reg];
  }
}

// ---------------- assemble c = (c1+c2)/2 from closed form; loss partials ----------
__global__ void k_assemble(const float* __restrict__ Spart, const float* __restrict__ stats,
                           float* __restrict__ lossPart) {
  int c = blockIdx.x, tid = threadIdx.x;
  float muT = stats[0 * 512 + c], rsT = stats[1 * 512 + c], swT = stats[2 * 512 + c];
  float muV = stats[6 * 512 + c], rsV = stats[7 * 512 + c], swV = stats[8 * 512 + c];
  const float W = 64.0f, invB = 1.0f / 64.0f;
  float on = 0, off = 0;
  for (int d = tid; d < 512; d += 256) {
    float s1 = 0, s2 = 0;
    for (int sl = 0; sl < 4; sl++) {
      s1 += Spart[((size_t)sl * 512 + c) * 512 + d];
      s2 += Spart[((size_t)(4 + sl) * 512 + c) * 512 + d];
    }
    float muMV = stats[3 * 512 + d], rsMV = stats[4 * 512 + d], swMV = stats[5 * 512 + d];
    float muMT = stats[9 * 512 + d], rsMT = stats[10 * 512 + d], swMT = stats[11 * 512 + d];
    float c1 = (s1 - muT * swMV - muMV * swT + muT * muMV * W) * rsT * rsMV * invB;
    float c2 = (s2 - muV * swMT - muMT * swV + muV * muMT * W) * rsV * rsMT * invB;
    float cc = 0.5f * (c1 + c2);
    if (d == c) { float dd = cc - 1.0f; on += dd * dd; }
    else off += cc * cc;
  }
  __shared__ float r1[4], r2[4];
  for (int s = 1; s < 64; s <<= 1) { on += __shfl_xor(on, s); off += __shfl_xor(off, s); }
  if ((tid & 63) == 0) { r1[tid >> 6] = on; r2[tid >> 6] = off; }
  __syncthreads();
  if (tid == 0) {
    lossPart[c * 2] = r1[0] + r1[1] + r1[2] + r1[3];
    lossPart[c * 2 + 1] = r2[0] + r2[1] + r2[2] + r2[3];
  }
}

__global__ void k_loss(const float* __restrict__ lossPart, float* __restrict__ out) {
  int tid = threadIdx.x;
  float on = 0, off = 0;
  for (int i = tid; i < 512; i += 256) { on += lossPart[2 * i]; off += lossPart[2 * i + 1]; }
  __shared__ float r1[4], r2[4];
  for (int s = 1; s < 64; s <<= 1) { on += __shfl_xor(on, s); off += __shfl_xor(off, s); }
  if ((tid & 63) == 0) { r1[tid >> 6] = on; r2[tid >> 6] = off; }
  __syncthreads();
  if (tid == 0)
    out[8192] = 0.1f * ((r1[0] + r1[1] + r1[2] + r1[3]) +
                        0.06f * (r2[0] + r2[1] + r2[2] + r2[3]));
}

extern "C" void kernel_launch(void* const* d_in, const int* in_sizes, int n_in,
                              void* d_out, int out_size, void* d_ws, size_t ws_size,
                              hipStream_t stream) {
  (void)in_sizes; (void)n_in; (void)out_size; (void)ws_size;
  const float* v_tok  = (const float*)d_in[1];
  const float* t_tok  = (const float*)d_in[3];
  const float* Wv_tok = (const float*)d_in[8];
  const float* Wt_tok = (const float*)d_in[10];
  const float* bv_tok = (const float*)d_in[9];
  const float* bt_tok = (const float*)d_in[11];
  const float* wv_fc  = (const float*)d_in[12];
  const float* bv_fc  = (const float*)d_in[13];
  const float* wt_fc  = (const float*)d_in[14];
  const float* bt_fc  = (const float*)d_in[15];
  const int*   tlen   = (const int*)d_in[16];
  float* out = (float*)d_out;

  char* wsb = (char*)d_ws;
  // --- R0 (27,131,904 B): phase 1 {v_tok_bf, t_tok_bf, WvT, WtT};
  //     after proj: {ve_bf, te_bf, Spart} (lifetime-disjoint, stream-ordered)
  short* v_tok_bf = (short*)wsb;                       // 9,633,792 sh
  short* t_tok_bf = v_tok_bf + (size_t)9633792;        // 3,145,728 sh
  short* WvT      = t_tok_bf + (size_t)3145728;        //   393,216 sh
  short* WtT      = WvT + (size_t)393216;              //   393,216 sh
  short* ve_bf    = (short*)wsb;                       // 6,422,528 sh (alias v_tok_bf)
  short* te_bf    = ve_bf + (size_t)6422528;           // 2,097,152 sh
  float* Spart    = (float*)(wsb + 17039360);          // 8*512*512 f (alias tail)
  // --- R1 (34,078,720 B): phase 1 {ve, te fp32}; after normfc: transposed operands
  float* ve  = (float*)(wsb + 27131904);               // 6,422,528 f
  float* te  = ve + (size_t)6422528;                   // 2,097,152 f
  short* tTw = (short*)(wsb + 27131904);               // 512*4096  (alias)
  short* mvT = tTw + (size_t)2097152;                  // 512*4096
  short* vTw = mvT + (size_t)2097152;                  // 512*12544
  short* mtT = vTw + (size_t)6422528;                  // 512*12544
  // --- R2 smalls
  float* vwf = (float*)(wsb + 61210624);               // 12544
  float* twf = vwf + 12544;                            // 4096
  int* gMT = (int*)(twf + 4096);                       // 12544
  int* gMV = gMT + 12544;                              // 4096
  float* statPart = (float*)(gMV + 4096);              // 4*13*512*3
  float* stats = statPart + 79872;                     // 12*512
  float* lossPart = stats + 6144;                      // 1024

  k_tobf16<<<4704, 256, 0, stream>>>(v_tok, v_tok_bf, 1204224);
  k_tobf16<<<1536, 256, 0, stream>>>(t_tok, t_tok_bf, 393216);
  k_transpose_bf<<<dim3(24, 16, 2), dim3(32, 8), 0, stream>>>(Wv_tok, Wt_tok, WvT, WtT);
  k_proj_mfma<<<dim3(8, 98), 256, 0, stream>>>(v_tok_bf, WvT, bv_tok, ve);
  k_proj_mfma<<<dim3(8, 32), 256, 0, stream>>>(t_tok_bf, WtT, bt_tok, te);
  k_normfc<<<3136, 256, 0, stream>>>(ve, wv_fc, bv_fc, vwf, ve_bf, 12544);
  k_normfc<<<1024, 256, 0, stream>>>(te, wt_fc, bt_fc, twf, te_bf, 4096);
  k_softmax<<<128, 256, 0, stream>>>(vwf, twf, tlen);
  k_sim<<<dim3(64, 64), 256, 0, stream>>>(ve_bf, te_bf, vwf, twf, out, gMT, gMV);
  k_stats<<<dim3(8, 13, 4), 256, 0, stream>>>(ve_bf, te_bf, gMT, gMV, vwf, twf, statPart);
  k_statfin<<<4, 512, 0, stream>>>(statPart, stats);
  k_materialize<<<dim3(196, 8, 4), 256, 0, stream>>>(ve_bf, te_bf, gMT, gMV, vwf, twf,
                                                     tTw, mvT, vTw, mtT);
  k_wgemm2<<<dim3(4, 8, 8), 256, 0, stream>>>(tTw, mvT, vTw, mtT, Spart);
  k_assemble<<<512, 256, 0, stream>>>(Spart, stats, lossPart);
  k_loss<<<1, 256, 0, stream>>>(lossPart, out);
}

// Round 5
// 380.318 us; speedup vs baseline: 4.6509x; 1.0327x over previous
//
#include <hip/hip_runtime.h>
#include <cstddef>

#define EDIM 512
#define KDIM 768
#define NB 64
#define NV 196
#define NT 64
#define MROWS_V (NB * NV) /* 12544 */
#define MROWS_T (NB * NT) /* 4096  */

typedef __attribute__((ext_vector_type(8))) short bf16x8;
typedef __attribute__((ext_vector_type(4))) float f32x4;

static __device__ inline unsigned short f2bf(float f) {  // round-to-nearest-even
  unsigned u = __float_as_uint(f);
  unsigned r = (u + 0x7fff + ((u >> 16) & 1)) >> 16;
  return (unsigned short)r;
}
static __device__ inline float bf2f(short s) {
  return __uint_as_float(((unsigned)(unsigned short)s) << 16);
}

// async global->LDS, 16B per lane; LDS dest = wave-uniform base + lane*16
static __device__ __forceinline__ void gload16(const void* g, void* l) {
  __builtin_amdgcn_global_load_lds(
      (const __attribute__((address_space(1))) void*)g,
      (__attribute__((address_space(3))) void*)l, 16, 0, 0);
}

// ---------------- fp32 -> bf16 elementwise (8 elems/thread) ----------------
__global__ void k_tobf16(const float* __restrict__ in, short* __restrict__ outp, int n8) {
  int i = blockIdx.x * 256 + threadIdx.x;
  if (i >= n8) return;
  float4 a = *(const float4*)(in + (size_t)i * 8);
  float4 b = *(const float4*)(in + (size_t)i * 8 + 4);
  bf16x8 v;
  v[0] = (short)f2bf(a.x); v[1] = (short)f2bf(a.y);
  v[2] = (short)f2bf(a.z); v[3] = (short)f2bf(a.w);
  v[4] = (short)f2bf(b.x); v[5] = (short)f2bf(b.y);
  v[6] = (short)f2bf(b.z); v[7] = (short)f2bf(b.w);
  *(bf16x8*)(outp + (size_t)i * 8) = v;
}

// ---------------- transpose W [768x512] fp32 -> WT [512x768] bf16 ----------------
__global__ void k_transpose_bf(const float* __restrict__ W0, const float* __restrict__ W1,
                               short* __restrict__ T0, short* __restrict__ T1) {
  __shared__ float tile[32][33];
  const float* W = blockIdx.z ? W1 : W0;
  short*       T = blockIdx.z ? T1 : T0;
  int k0 = blockIdx.x * 32;
  int n0 = blockIdx.y * 32;
  int tx = threadIdx.x, ty = threadIdx.y;
  for (int i = ty; i < 32; i += 8)
    tile[i][tx] = W[(size_t)(k0 + i) * EDIM + n0 + tx];
  __syncthreads();
  for (int i = ty; i < 32; i += 8)
    T[(size_t)(n0 + i) * KDIM + k0 + tx] = (short)f2bf(tile[tx][i]);
}

// ---------- MFMA projection: C[r,n] = sum_k X[r,k]*WT[n,k] + bias[n] (fp32 out) ----
__global__ __launch_bounds__(256, 4) void k_proj_mfma(
    const short* __restrict__ Xbf, const short* __restrict__ WT,
    const float* __restrict__ bias, float* __restrict__ C) {
  __shared__ short As[128 * 44];   // 88 B stride: <=2-way banks (free)
  __shared__ short Bs[64 * 44];
  int n0 = blockIdx.x * 64;
  int r0 = blockIdx.y * 128;
  int tid = threadIdx.x;
  int w = tid >> 6, lane = tid & 63, lg = lane >> 4, li = lane & 15;
  f32x4 acc[2][4];
#pragma unroll
  for (int i = 0; i < 2; ++i)
#pragma unroll
    for (int j = 0; j < 4; ++j) acc[i][j] = (f32x4){0.f, 0.f, 0.f, 0.f};
  for (int kc = 0; kc < KDIM / 32; ++kc) {
    int k0 = kc << 5;
    __syncthreads();
#pragma unroll
    for (int uu = 0; uu < 2; ++uu) {   // A: 128 rows x 4 segs
      int u = tid + uu * 256;
      int r = u >> 2, seg = (u & 3) << 3;
      *(bf16x8*)(As + r * 44 + seg) =
          *(const bf16x8*)(Xbf + (size_t)(r0 + r) * KDIM + k0 + seg);
    }
    {   // B: 64 rows x 4 segs
      int t = tid >> 2, seg = (tid & 3) << 3;
      *(bf16x8*)(Bs + t * 44 + seg) =
          *(const bf16x8*)(WT + (size_t)(n0 + t) * KDIM + k0 + seg);
    }
    __syncthreads();
    bf16x8 bfr[4];
#pragma unroll
    for (int j = 0; j < 4; ++j)
      bfr[j] = *(const bf16x8*)(Bs + (j * 16 + li) * 44 + lg * 8);
#pragma unroll
    for (int i = 0; i < 2; ++i) {
      bf16x8 afr = *(const bf16x8*)(As + ((w * 2 + i) * 16 + li) * 44 + lg * 8);
#pragma unroll
      for (int j = 0; j < 4; ++j)
        acc[i][j] = __builtin_amdgcn_mfma_f32_16x16x32_bf16(afr, bfr[j], acc[i][j], 0, 0, 0);
    }
  }
#pragma unroll
  for (int j = 0; j < 4; ++j) {
    int n = n0 + j * 16 + li;
    float bb = bias[n];
#pragma unroll
    for (int i = 0; i < 2; ++i)
#pragma unroll
      for (int reg = 0; reg < 4; ++reg)
        C[(size_t)(r0 + (w * 2 + i) * 16 + lg * 4 + reg) * EDIM + n] = acc[i][j][reg] + bb;
  }
}

// ------- per-row: fc scalar (pre-norm) + l2 normalize -> bf16 copy only -------
__global__ void k_normfc(const float* __restrict__ M, const float* __restrict__ fcw,
                         const float* __restrict__ fcb, float* __restrict__ wout,
                         short* __restrict__ Mbf, int nrows) {
  int row = blockIdx.x * 4 + (threadIdx.x >> 6);
  int lane = threadIdx.x & 63;
  if (row >= nrows) return;
  const float* p = M + (size_t)row * EDIM;
  float4 a0 = *(const float4*)(p + lane * 8);
  float4 a1 = *(const float4*)(p + lane * 8 + 4);
  float4 w0 = *(const float4*)(fcw + lane * 8);
  float4 w1 = *(const float4*)(fcw + lane * 8 + 4);
  float dot = a0.x * w0.x + a0.y * w0.y + a0.z * w0.z + a0.w * w0.w +
              a1.x * w1.x + a1.y * w1.y + a1.z * w1.z + a1.w * w1.w;
  float ss = a0.x * a0.x + a0.y * a0.y + a0.z * a0.z + a0.w * a0.w +
             a1.x * a1.x + a1.y * a1.y + a1.z * a1.z + a1.w * a1.w;
  for (int s = 1; s < 64; s <<= 1) {
    dot += __shfl_xor(dot, s);
    ss += __shfl_xor(ss, s);
  }
  float inv = 1.0f / fmaxf(sqrtf(ss), 1e-12f);
  bf16x8 bv;
  bv[0] = (short)f2bf(a0.x * inv); bv[1] = (short)f2bf(a0.y * inv);
  bv[2] = (short)f2bf(a0.z * inv); bv[3] = (short)f2bf(a0.w * inv);
  bv[4] = (short)f2bf(a1.x * inv); bv[5] = (short)f2bf(a1.y * inv);
  bv[6] = (short)f2bf(a1.z * inv); bv[7] = (short)f2bf(a1.w * inv);
  *(bf16x8*)(Mbf + (size_t)row * EDIM + lane * 8) = bv;
  if (lane == 0) wout[row] = dot + fcb[0];
}

// ---------------- softmax: blocks 0..63 vw rows (196), 64..127 tw rows (64, masked) ----
__global__ void k_softmax(float* __restrict__ vwf, float* __restrict__ twf,
                          const int* __restrict__ tlen) {
  __shared__ float red[8];
  int tid = threadIdx.x;
  if (blockIdx.x < 64) {
    int b = blockIdx.x;
    float x = (tid < NV) ? vwf[b * NV + tid] : -1e30f;
    float m = x;
    for (int s = 1; s < 64; s <<= 1) m = fmaxf(m, __shfl_xor(m, s));
    if ((tid & 63) == 0) red[tid >> 6] = m;
    __syncthreads();
    m = fmaxf(fmaxf(red[0], red[1]), fmaxf(red[2], red[3]));
    float e = (tid < NV) ? expf(x - m) : 0.0f;
    float s = e;
    for (int st = 1; st < 64; st <<= 1) s += __shfl_xor(s, st);
    if ((tid & 63) == 0) red[4 + (tid >> 6)] = s;
    __syncthreads();
    s = red[4] + red[5] + red[6] + red[7];
    if (tid < NV) vwf[b * NV + tid] = e / s;
  } else {
    int b = blockIdx.x - 64;
    if (tid < 64) {
      int len = tlen[b];
      float x = twf[b * NT + tid];
      bool valid = tid < len;
      float xv = valid ? x : -1e30f;
      float m = xv;
      for (int s = 1; s < 64; s <<= 1) m = fmaxf(m, __shfl_xor(m, s));
      float e = valid ? expf(x - m) : 0.0f;
      float s = e;
      for (int st = 1; st < 64; st <<= 1) s += __shfl_xor(s, st);
      twf[b * NT + tid] = e / s;
    }
  }
}

// ---------------- MFMA sim kernel: one block per (b, q-pair) ------------------------
// Block handles q0=2qq, q1=2qq+1 (te rows contiguous). Wave w owns row-tiles
// {4w..4w+3} (rows padded to 256) x 8 col-tiles (q0's 4 + q1's 4).
// Staging via global_load_lds (linear LDS, 64B rows) with source-side seg XOR
// swizzle; frag reads use seg = lg ^ (li&3)  -> uniform bank spread.
__global__ __launch_bounds__(256, 2) void k_sim(
    const short* __restrict__ ve_bf, const short* __restrict__ te_bf,
    const float* __restrict__ vwf, const float* __restrict__ twf,
    float* __restrict__ out, int* __restrict__ gMT, int* __restrict__ gMV) {
  __shared__ short As[256 * 32];   // linear, 64B row stride
  __shared__ short Bs[128 * 32];
  __shared__ float colv[4][128];
  __shared__ int   coli[4][128];
  __shared__ float redp0[4], redp1[4];
  int qq = blockIdx.x, b = blockIdx.y;
  int tid = threadIdx.x;
  int w = tid >> 6, lane = tid & 63, lg = lane >> 4, li = lane & 15;
  const short* Abf = ve_bf + (size_t)b * NV * EDIM;
  const short* Bbf = te_bf + (size_t)qq * 128 * EDIM;
  f32x4 acc[4][8];
#pragma unroll
  for (int i = 0; i < 4; ++i)
#pragma unroll
    for (int j = 0; j < 8; ++j) acc[i][j] = (f32x4){0.f, 0.f, 0.f, 0.f};

  int swz = li & 3;
  for (int kc = 0; kc < 16; ++kc) {
    int k0 = kc << 5;
    __syncthreads();   // previous chunk's frag reads done before DMA overwrite
    // B: 128 rows x 4 segs = 512 units
#pragma unroll
    for (int uu = 0; uu < 2; ++uu) {
      int u0 = uu * 256 + w * 64;
      int u = u0 + lane;
      int row = u >> 2, seg = u & 3;
      int ss = seg ^ (row & 3);
      gload16(Bbf + (size_t)row * EDIM + k0 + ss * 8, Bs + u0 * 8);
    }
    // A: 784 valid units (rows clamped past 195; LDS rows >=208 never staged, masked)
#pragma unroll
    for (int uu = 0; uu < 4; ++uu) {
      int u0 = uu * 256 + w * 64;
      if (u0 < NV * 4) {
        int u = u0 + lane;
        int row = u >> 2;
        if (row > NV - 1) row = NV - 1;
        int seg = u & 3;
        int ss = seg ^ (row & 3);
        gload16(Abf + (size_t)row * EDIM + k0 + ss * 8, As + u0 * 8);
      }
    }
    __syncthreads();   // drains vmcnt (compiler emits) -> data visible
    bf16x8 bfr[8];
#pragma unroll
    for (int j = 0; j < 8; ++j)
      bfr[j] = *(const bf16x8*)(Bs + (j * 16 + li) * 32 + (lg ^ swz) * 8);
#pragma unroll
    for (int i = 0; i < 4; ++i) {
      bf16x8 afr = *(const bf16x8*)(As + ((w * 4 + i) * 16 + li) * 32 + (lg ^ swz) * 8);
#pragma unroll
      for (int j = 0; j < 8; ++j)
        acc[i][j] = __builtin_amdgcn_mfma_f32_16x16x32_bf16(afr, bfr[j], acc[i][j], 0, 0, 0);
    }
  }

  bool diag0 = (b == 2 * qq), diag1 = (b == 2 * qq + 1);
  // ---- row (over t) max+argmax per q; C layout: row=tile*16+lg*4+reg, col=j*16+li
  float ip0 = 0.f, ip1 = 0.f;
#pragma unroll
  for (int i = 0; i < 4; ++i) {
#pragma unroll
    for (int reg = 0; reg < 4; ++reg) {
      int v = (w * 4 + i) * 16 + lg * 4 + reg;
      float m = acc[i][0][reg];
      int ti = li;
#pragma unroll
      for (int j = 1; j < 4; ++j) {
        float vv = acc[i][j][reg];
        int t = j * 16 + li;
        if (vv > m) { m = vv; ti = t; }   // t ascending -> first-index kept
      }
      for (int d = 1; d < 16; d <<= 1) {  // within li-group (same row)
        float om = __shfl_xor(m, d);
        int oi = __shfl_xor(ti, d);
        if (om > m || (om == m && oi < ti)) { m = om; ti = oi; }
      }
      float m1 = acc[i][4][reg];
      int ti1 = li;
#pragma unroll
      for (int j = 5; j < 8; ++j) {
        float vv = acc[i][j][reg];
        int t = (j - 4) * 16 + li;
        if (vv > m1) { m1 = vv; ti1 = t; }
      }
      for (int d = 1; d < 16; d <<= 1) {
        float om = __shfl_xor(m1, d);
        int oi = __shfl_xor(ti1, d);
        if (om > m1 || (om == m1 && oi < ti1)) { m1 = om; ti1 = oi; }
      }
      if (li == 0 && v < NV) {
        float wv = vwf[b * NV + v];
        ip0 += wv * m;
        ip1 += wv * m1;
        if (diag0) gMT[b * NV + v] = b * NT + ti;
        if (diag1) gMT[b * NV + v] = b * NT + ti1;
      }
    }
  }
  for (int d = 1; d < 64; d <<= 1) {
    ip0 += __shfl_xor(ip0, d);
    ip1 += __shfl_xor(ip1, d);
  }
  if (lane == 0) { redp0[w] = ip0; redp1[w] = ip1; }
  // ---- col (over v) max+argmax for this wave's rows, all 128 cols
  float cm[8]; int cv[8];
#pragma unroll
  for (int j = 0; j < 8; ++j) { cm[j] = -3.0e38f; cv[j] = 0; }
#pragma unroll
  for (int i = 0; i < 4; ++i)
#pragma unroll
    for (int reg = 0; reg < 4; ++reg) {
      int v = (w * 4 + i) * 16 + lg * 4 + reg;
      bool ok = v < NV;
#pragma unroll
      for (int j = 0; j < 8; ++j) {
        float s = ok ? acc[i][j][reg] : -3.0e38f;
        if (s > cm[j]) { cm[j] = s; cv[j] = v; }  // v ascending per lane
      }
    }
#pragma unroll
  for (int j = 0; j < 8; ++j) {
    for (int d = 16; d < 64; d <<= 1) {   // mixes lg groups (same col)
      float om = __shfl_xor(cm[j], d);
      int ov = __shfl_xor(cv[j], d);
      if (om > cm[j] || (om == cm[j] && ov < cv[j])) { cm[j] = om; cv[j] = ov; }
    }
    if (lg == 0) { colv[w][j * 16 + li] = cm[j]; coli[w][j * 16 + li] = cv[j]; }
  }
  __syncthreads();
  if (tid < 128) {   // wave0 -> q0 cols, wave1 -> q1 cols
    int t = tid;
    float m = colv[0][t];
    int bi = coli[0][t];
#pragma unroll
    for (int w2 = 1; w2 < 4; ++w2) {
      float om = colv[w2][t];
      int ov = coli[w2][t];
      if (om > m || (om == m && ov < bi)) { m = om; bi = ov; }
    }
    int q = 2 * qq + (t >> 6);
    int tt = t & 63;
    if (b == q) gMV[b * NT + tt] = b * NV + bi;
    float p = twf[q * NT + tt] * m;
    for (int d = 1; d < 64; d <<= 1) p += __shfl_xor(p, d);
    if ((tid & 63) == 0) out[4096 + b * 64 + q] = p;
  }
  if (tid == 0) {
    out[b * 64 + 2 * qq]     = redp0[0] + redp0[1] + redp0[2] + redp0[3];
    out[b * 64 + 2 * qq + 1] = redp1[0] + redp1[1] + redp1[2] + redp1[3];
  }
}

// ---------------- column stats from bf16 (sum, sumsq, weighted sum) ------
__global__ void k_stats(const short* __restrict__ ve_bf, const short* __restrict__ te_bf,
                        const int* __restrict__ gMT, const int* __restrict__ gMV,
                        const float* __restrict__ vwf, const float* __restrict__ twf,
                        float* __restrict__ statPart) {
  int stripe = blockIdx.x, chunk = blockIdx.y, m = blockIdx.z;
  int R = (m < 2) ? MROWS_T : MROWS_V;
  int nchunk = (R + 1023) >> 10;
  if (chunk >= nchunk) return;
  const short* M; const int* g; const float* w;
  if (m == 0)      { M = te_bf; g = 0;   w = twf; }
  else if (m == 1) { M = ve_bf; g = gMV; w = twf; }
  else if (m == 2) { M = ve_bf; g = 0;   w = vwf; }
  else             { M = te_bf; g = gMT; w = vwf; }
  int col = stripe * 64 + (threadIdx.x & 63);
  int rg = threadIdx.x >> 6;
  int r0 = chunk << 10;
  int r1 = min(r0 + 1024, R);
  float s = 0, ss = 0, sw = 0;
  for (int r = r0 + rg; r < r1; r += 4) {
    int row = g ? g[r] : r;
    float x = bf2f(M[(size_t)row * EDIM + col]);
    s += x; ss += x * x; sw += w[r] * x;
  }
  __shared__ float red[3][256];
  red[0][threadIdx.x] = s; red[1][threadIdx.x] = ss; red[2][threadIdx.x] = sw;
  __syncthreads();
  if (threadIdx.x < 64) {
    int c = threadIdx.x;
    float S  = red[0][c] + red[0][c + 64] + red[0][c + 128] + red[0][c + 192];
    float SS = red[1][c] + red[1][c + 64] + red[1][c + 128] + red[1][c + 192];
    float SW = red[2][c] + red[2][c + 64] + red[2][c + 128] + red[2][c + 192];
    size_t idx = ((size_t)(m * 13 + chunk) * 512 + stripe * 64 + c) * 3;
    statPart[idx] = S; statPart[idx + 1] = SS; statPart[idx + 2] = SW;
  }
}

__global__ void k_statfin(const float* __restrict__ statPart, float* __restrict__ stats) {
  int m = blockIdx.x, c = threadIdx.x;
  int R = (m < 2) ? MROWS_T : MROWS_V;
  int nchunk = (R + 1023) >> 10;
  float s = 0, ss = 0, sw = 0;
  for (int ch = 0; ch < nchunk; ch++) {
    size_t idx = ((size_t)(m * 13 + ch) * 512 + c) * 3;
    s += statPart[idx]; ss += statPart[idx + 1]; sw += statPart[idx + 2];
  }
  float mean = s / R;
  float var = (ss - s * mean) / (R - 1);  // ddof=1
  float rstd = 1.0f / sqrtf(var);
  stats[(m * 3 + 0) * 512 + c] = mean;
  stats[(m * 3 + 1) * 512 + c] = rstd;
  stats[(m * 3 + 2) * 512 + c] = sw;
}

// ------- transpose-materialize a-contiguous bf16 operands (w and gathers folded) ----
__global__ void k_materialize(const short* __restrict__ ve_bf, const short* __restrict__ te_bf,
                              const int* __restrict__ gMT, const int* __restrict__ gMV,
                              const float* __restrict__ vwf, const float* __restrict__ twf,
                              short* __restrict__ tTw, short* __restrict__ mvT,
                              short* __restrict__ vTw, short* __restrict__ mtT) {
  int z = blockIdx.z;
  int at = blockIdx.x, ct = blockIdx.y;
  int K = (z == 2 || z == 3) ? MROWS_V : MROWS_T;
  if (at * 64 >= K) return;
  const short* src; const int* g = 0; const float* w = 0; short* dst;
  if (z == 0)      { src = te_bf; w = twf; dst = tTw; }
  else if (z == 1) { src = ve_bf; g = gMV; dst = mvT; }
  else if (z == 2) { src = ve_bf; w = vwf; dst = vTw; }
  else             { src = te_bf; g = gMT; dst = mtT; }
  __shared__ float tile[64][67];
  int tid = threadIdx.x;
  for (int u = tid; u < 512; u += 256) {
    int a = u >> 3, cseg = (u & 7) << 3;
    int ga = at * 64 + a;
    int row = g ? g[ga] : ga;
    bf16x8 vv = *(const bf16x8*)(src + (size_t)row * EDIM + ct * 64 + cseg);
    float wa = w ? w[ga] : 1.0f;
#pragma unroll
    for (int j = 0; j < 8; j++) tile[a][cseg + j] = wa * bf2f(vv[j]);
  }
  __syncthreads();
  for (int u = tid; u < 512; u += 256) {
    int c = u >> 3, aseg = (u & 7) << 3;
    bf16x8 ov;
#pragma unroll
    for (int j = 0; j < 8; j++) ov[j] = (short)f2bf(tile[aseg + j][c]);
    *(bf16x8*)(dst + (size_t)(ct * 64 + c) * K + at * 64 + aseg) = ov;
  }
}

// ------- MFMA weighted GEMM: Spart[z][c][d] = sum_a AT[c][a]*BT[d][a] (split-K 4) ----
__global__ __launch_bounds__(256, 4) void k_wgemm2(
    const short* __restrict__ tTw, const short* __restrict__ mvT,
    const short* __restrict__ vTw, const short* __restrict__ mtT,
    float* __restrict__ Spart) {
  __shared__ short As[128 * 44];
  __shared__ short Bs[64 * 44];
  int c0 = blockIdx.x * 128, d0 = blockIdx.y * 64;
  int z = blockIdx.z;
  int which = z >> 2, slice = z & 3;
  const short* A = which ? vTw : tTw;
  const short* B = which ? mtT : mvT;
  int K = which ? MROWS_V : MROWS_T;
  int nch = (K >> 2) >> 5;             // 98 or 32 chunks of 32
  int a0 = slice * (K >> 2);
  int tid = threadIdx.x;
  int w = tid >> 6, lane = tid & 63, lg = lane >> 4, li = lane & 15;
  f32x4 acc[2][4];
#pragma unroll
  for (int i = 0; i < 2; ++i)
#pragma unroll
    for (int j = 0; j < 4; ++j) acc[i][j] = (f32x4){0.f, 0.f, 0.f, 0.f};
  for (int ch = 0; ch < nch; ++ch) {
    int ak = a0 + (ch << 5);
    __syncthreads();
#pragma unroll
    for (int uu = 0; uu < 2; ++uu) {
      int u = tid + uu * 256;
      int r = u >> 2, seg = (u & 3) << 3;
      *(bf16x8*)(As + r * 44 + seg) = *(const bf16x8*)(A + (size_t)(c0 + r) * K + ak + seg);
    }
    {
      int t = tid >> 2, seg = (tid & 3) << 3;
      *(bf16x8*)(Bs + t * 44 + seg) = *(const bf16x8*)(B + (size_t)(d0 + t) * K + ak + seg);
    }
    __syncthreads();
    bf16x8 bfr[4];
#pragma unroll
    for (int j = 0; j < 4; ++j)
      bfr[j] = *(const bf16x8*)(Bs + (j * 16 + li) * 44 + lg * 8);
#pragma unroll
    for (int i = 0; i < 2; ++i) {
      bf16x8 afr = *(const bf16x8*)(As + ((w * 2 + i) * 16 + li) * 44 + lg * 8);
#pragma unroll
      for (int j = 0; j < 4; ++j)
        acc[i][j] = __builtin_amdgcn_mfma_f32_16x16x32_bf16(afr, bfr[j], acc[i][j], 0, 0, 0);
    }
  }
  float* outp = Spart + (size_t)z * 512 * 512;
#pragma unroll
  for (int j = 0; j < 4; ++j) {
    int d = d0 + j * 16 + li;
#pragma unroll
    for (int i = 0; i < 2; ++i)
#pragma unroll
      for (int reg = 0; reg < 4; ++reg)
        outp[(size_t)(c0 + (w * 2 + i) * 16 + lg * 4 + reg) * 512 + d] = acc[i][j][reg];
  }
}

// ---------------- assemble c = (c1+c2)/2 from closed form; loss partials ----------
__global__ void k_assemble(const float* __restrict__ Spart, const float* __restrict__ stats,
                           float* __restrict__ lossPart) {
  int c = blockIdx.x, tid = threadIdx.x;
  float muT = stats[0 * 512 + c], rsT = stats[1 * 512 + c], swT = stats[2 * 512 + c];
  float muV = stats[6 * 512 + c], rsV = stats[7 * 512 + c], swV = stats[8 * 512 + c];
  const float W = 64.0f, invB = 1.0f / 64.0f;
  float on = 0, off = 0;
  for (int d = tid; d < 512; d += 256) {
    float s1 = 0, s2 = 0;
    for (int sl = 0; sl < 4; sl++) {
      s1 += Spart[((size_t)sl * 512 + c) * 512 + d];
      s2 += Spart[((size_t)(4 + sl) * 512 + c) * 512 + d];
    }
    float muMV = stats[3 * 512 + d], rsMV = stats[4 * 512 + d], swMV = stats[5 * 512 + d];
    float muMT = stats[9 * 512 + d], rsMT = stats[10 * 512 + d], swMT = stats[11 * 512 + d];
    float c1 = (s1 - muT * swMV - muMV * swT + muT * muMV * W) * rsT * rsMV * invB;
    float c2 = (s2 - muV * swMT - muMT * swV + muV * muMT * W) * rsV * rsMT * invB;
    float cc = 0.5f * (c1 + c2);
    if (d == c) { float dd = cc - 1.0f; on += dd * dd; }
    else off += cc * cc;
  }
  __shared__ float r1[4], r2[4];
  for (int s = 1; s < 64; s <<= 1) { on += __shfl_xor(on, s); off += __shfl_xor(off, s); }
  if ((tid & 63) == 0) { r1[tid >> 6] = on; r2[tid >> 6] = off; }
  __syncthreads();
  if (tid == 0) {
    lossPart[c * 2] = r1[0] + r1[1] + r1[2] + r1[3];
    lossPart[c * 2 + 1] = r2[0] + r2[1] + r2[2] + r2[3];
  }
}

__global__ void k_loss(const float* __restrict__ lossPart, float* __restrict__ out) {
  int tid = threadIdx.x;
  float on = 0, off = 0;
  for (int i = tid; i < 512; i += 256) { on += lossPart[2 * i]; off += lossPart[2 * i + 1]; }
  __shared__ float r1[4], r2[4];
  for (int s = 1; s < 64; s <<= 1) { on += __shfl_xor(on, s); off += __shfl_xor(off, s); }
  if ((tid & 63) == 0) { r1[tid >> 6] = on; r2[tid >> 6] = off; }
  __syncthreads();
  if (tid == 0)
    out[8192] = 0.1f * ((r1[0] + r1[1] + r1[2] + r1[3]) +
                        0.06f * (r2[0] + r2[1] + r2[2] + r2[3]));
}

extern "C" void kernel_launch(void* const* d_in, const int* in_sizes, int n_in,
                              void* d_out, int out_size, void* d_ws, size_t ws_size,
                              hipStream_t stream) {
  (void)in_sizes; (void)n_in; (void)out_size; (void)ws_size;
  const float* v_tok  = (const float*)d_in[1];
  const float* t_tok  = (const float*)d_in[3];
  const float* Wv_tok = (const float*)d_in[8];
  const float* Wt_tok = (const float*)d_in[10];
  const float* bv_tok = (const float*)d_in[9];
  const float* bt_tok = (const float*)d_in[11];
  const float* wv_fc  = (const float*)d_in[12];
  const float* bv_fc  = (const float*)d_in[13];
  const float* wt_fc  = (const float*)d_in[14];
  const float* bt_fc  = (const float*)d_in[15];
  const int*   tlen   = (const int*)d_in[16];
  float* out = (float*)d_out;

  char* wsb = (char*)d_ws;
  // --- R0 (27,131,904 B): phase 1 {v_tok_bf, t_tok_bf, WvT, WtT};
  //     after proj: {ve_bf, te_bf, Spart} (lifetime-disjoint, stream-ordered)
  short* v_tok_bf = (short*)wsb;                       // 9,633,792 sh
  short* t_tok_bf = v_tok_bf + (size_t)9633792;        // 3,145,728 sh
  short* WvT      = t_tok_bf + (size_t)3145728;        //   393,216 sh
  short* WtT      = WvT + (size_t)393216;              //   393,216 sh
  short* ve_bf    = (short*)wsb;                       // 6,422,528 sh (alias v_tok_bf)
  short* te_bf    = ve_bf + (size_t)6422528;           // 2,097,152 sh
  float* Spart    = (float*)(wsb + 17039360);          // 8*512*512 f (alias tail)
  // --- R1 (34,078,720 B): phase 1 {ve, te fp32}; after normfc: transposed operands
  float* ve  = (float*)(wsb + 27131904);               // 6,422,528 f
  float* te  = ve + (size_t)6422528;                   // 2,097,152 f
  short* tTw = (short*)(wsb + 27131904);               // 512*4096  (alias)
  short* mvT = tTw + (size_t)2097152;                  // 512*4096
  short* vTw = mvT + (size_t)2097152;                  // 512*12544
  short* mtT = vTw + (size_t)6422528;                  // 512*12544
  // --- R2 smalls
  float* vwf = (float*)(wsb + 61210624);               // 12544
  float* twf = vwf + 12544;                            // 4096
  int* gMT = (int*)(twf + 4096);                       // 12544
  int* gMV = gMT + 12544;                              // 4096
  float* statPart = (float*)(gMV + 4096);              // 4*13*512*3
  float* stats = statPart + 79872;                     // 12*512
  float* lossPart = stats + 6144;                      // 1024

  k_tobf16<<<4704, 256, 0, stream>>>(v_tok, v_tok_bf, 1204224);
  k_tobf16<<<1536, 256, 0, stream>>>(t_tok, t_tok_bf, 393216);
  k_transpose_bf<<<dim3(24, 16, 2), dim3(32, 8), 0, stream>>>(Wv_tok, Wt_tok, WvT, WtT);
  k_proj_mfma<<<dim3(8, 98), 256, 0, stream>>>(v_tok_bf, WvT, bv_tok, ve);
  k_proj_mfma<<<dim3(8, 32), 256, 0, stream>>>(t_tok_bf, WtT, bt_tok, te);
  k_normfc<<<3136, 256, 0, stream>>>(ve, wv_fc, bv_fc, vwf, ve_bf, 12544);
  k_normfc<<<1024, 256, 0, stream>>>(te, wt_fc, bt_fc, twf, te_bf, 4096);
  k_softmax<<<128, 256, 0, stream>>>(vwf, twf, tlen);
  k_sim<<<dim3(32, 64), 256, 0, stream>>>(ve_bf, te_bf, vwf, twf, out, gMT, gMV);
  k_stats<<<dim3(8, 13, 4), 256, 0, stream>>>(ve_bf, te_bf, gMT, gMV, vwf, twf, statPart);
  k_statfin<<<4, 512, 0, stream>>>(statPart, stats);
  k_materialize<<<dim3(196, 8, 4), 256, 0, stream>>>(ve_bf, te_bf, gMT, gMV, vwf, twf,
                                                     tTw, mvT, vTw, mtT);
  k_wgemm2<<<dim3(4, 8, 8), 256, 0, stream>>>(tTw, mvT, vTw, mtT, Spart);
  k_assemble<<<512, 256, 0, stream>>>(Spart, stats, lossPart);
  k_loss<<<1, 256, 0, stream>>>(lossPart, out);
}

// Round 6
// 361.587 us; speedup vs baseline: 4.8918x; 1.0518x over previous
//
#include <hip/hip_runtime.h>
#include <cstddef>

#define EDIM 512
#define KDIM 768
#define NB 64
#define NV 196
#define NT 64
#define MROWS_V (NB * NV) /* 12544 */
#define MROWS_T (NB * NT) /* 4096  */

typedef __attribute__((ext_vector_type(8))) short bf16x8;
typedef __attribute__((ext_vector_type(4))) float f32x4;

static __device__ inline unsigned short f2bf(float f) {  // round-to-nearest-even
  unsigned u = __float_as_uint(f);
  unsigned r = (u + 0x7fff + ((u >> 16) & 1)) >> 16;
  return (unsigned short)r;
}
static __device__ inline float bf2f(short s) {
  return __uint_as_float(((unsigned)(unsigned short)s) << 16);
}

// async global->LDS, 16B per lane; LDS dest = wave-uniform base + lane*16
static __device__ __forceinline__ void gload16(const void* g, void* l) {
  __builtin_amdgcn_global_load_lds(
      (const __attribute__((address_space(1))) void*)g,
      (__attribute__((address_space(3))) void*)l, 16, 0, 0);
}

// ---------------- fp32 -> bf16 elementwise (8 elems/thread) ----------------
__global__ void k_tobf16(const float* __restrict__ in, short* __restrict__ outp, int n8) {
  int i = blockIdx.x * 256 + threadIdx.x;
  if (i >= n8) return;
  float4 a = *(const float4*)(in + (size_t)i * 8);
  float4 b = *(const float4*)(in + (size_t)i * 8 + 4);
  bf16x8 v;
  v[0] = (short)f2bf(a.x); v[1] = (short)f2bf(a.y);
  v[2] = (short)f2bf(a.z); v[3] = (short)f2bf(a.w);
  v[4] = (short)f2bf(b.x); v[5] = (short)f2bf(b.y);
  v[6] = (short)f2bf(b.z); v[7] = (short)f2bf(b.w);
  *(bf16x8*)(outp + (size_t)i * 8) = v;
}

// ---------------- transpose W [768x512] fp32 -> WT [512x768] bf16 ----------------
__global__ void k_transpose_bf(const float* __restrict__ W0, const float* __restrict__ W1,
                               short* __restrict__ T0, short* __restrict__ T1) {
  __shared__ float tile[32][33];
  const float* W = blockIdx.z ? W1 : W0;
  short*       T = blockIdx.z ? T1 : T0;
  int k0 = blockIdx.x * 32;
  int n0 = blockIdx.y * 32;
  int tx = threadIdx.x, ty = threadIdx.y;
  for (int i = ty; i < 32; i += 8)
    tile[i][tx] = W[(size_t)(k0 + i) * EDIM + n0 + tx];
  __syncthreads();
  for (int i = ty; i < 32; i += 8)
    T[(size_t)(n0 + i) * KDIM + k0 + tx] = (short)f2bf(tile[tx][i]);
}

// ---------- MFMA projection: C[r,n] = sum_k X[r,k]*WT[n,k] + bias[n] (fp32 out) ----
// dbuf + prefetch: stage(kc+1) issued before compute(kc); one barrier/kc.
__global__ __launch_bounds__(256, 4) void k_proj_mfma(
    const short* __restrict__ Xbf, const short* __restrict__ WT,
    const float* __restrict__ bias, float* __restrict__ C) {
  __shared__ short As[2][128 * 32];   // linear 64B rows
  __shared__ short Bs[2][64 * 32];
  int n0 = blockIdx.x * 64;
  int r0 = blockIdx.y * 128;
  int tid = threadIdx.x;
  int w = tid >> 6, lane = tid & 63, lg = lane >> 4, li = lane & 15;
  int swz = li & 3;

  auto stage = [&](int bb, int kc) {
    int k0 = kc << 5;
    short* Ad = &As[bb][0];
    short* Bd = &Bs[bb][0];
#pragma unroll
    for (int uu = 0; uu < 2; ++uu) {   // A: 128 rows x 4 segs = 512 units
      int u0 = uu * 256 + w * 64;
      int u = u0 + lane;
      int row = u >> 2, seg = u & 3;
      int ss = seg ^ (row & 3);
      gload16(Xbf + (size_t)(r0 + row) * KDIM + k0 + ss * 8, Ad + u0 * 8);
    }
    {                                   // B: 64 rows x 4 segs = 256 units
      int u0 = w * 64;
      int u = u0 + lane;
      int row = u >> 2, seg = u & 3;
      int ss = seg ^ (row & 3);
      gload16(WT + (size_t)(n0 + row) * KDIM + k0 + ss * 8, Bd + u0 * 8);
    }
  };

  f32x4 acc[2][4];
#pragma unroll
  for (int i = 0; i < 2; ++i)
#pragma unroll
    for (int j = 0; j < 4; ++j) acc[i][j] = (f32x4){0.f, 0.f, 0.f, 0.f};

  stage(0, 0);
  __syncthreads();   // vmcnt(0) drain + barrier: buf0 ready
  int cur = 0;
  for (int kc = 0; kc < KDIM / 32; ++kc) {
    if (kc < KDIM / 32 - 1) stage(cur ^ 1, kc + 1);  // prefetch overlaps compute
    const short* Ab = &As[cur][0];
    const short* Bb = &Bs[cur][0];
    bf16x8 bfr[4];
#pragma unroll
    for (int j = 0; j < 4; ++j)
      bfr[j] = *(const bf16x8*)(Bb + (j * 16 + li) * 32 + (lg ^ swz) * 8);
#pragma unroll
    for (int i = 0; i < 2; ++i) {
      bf16x8 afr = *(const bf16x8*)(Ab + ((w * 2 + i) * 16 + li) * 32 + (lg ^ swz) * 8);
#pragma unroll
      for (int j = 0; j < 4; ++j)
        acc[i][j] = __builtin_amdgcn_mfma_f32_16x16x32_bf16(afr, bfr[j], acc[i][j], 0, 0, 0);
    }
    __syncthreads();   // drains prefetch vmcnt after compute; guards dbuf reuse
    cur ^= 1;
  }
#pragma unroll
  for (int j = 0; j < 4; ++j) {
    int n = n0 + j * 16 + li;
    float bb = bias[n];
#pragma unroll
    for (int i = 0; i < 2; ++i)
#pragma unroll
      for (int reg = 0; reg < 4; ++reg)
        C[(size_t)(r0 + (w * 2 + i) * 16 + lg * 4 + reg) * EDIM + n] = acc[i][j][reg] + bb;
  }
}

// ------- per-row: fc scalar (pre-norm) + l2 normalize -> bf16 copy only -------
__global__ void k_normfc(const float* __restrict__ M, const float* __restrict__ fcw,
                         const float* __restrict__ fcb, float* __restrict__ wout,
                         short* __restrict__ Mbf, int nrows) {
  int row = blockIdx.x * 4 + (threadIdx.x >> 6);
  int lane = threadIdx.x & 63;
  if (row >= nrows) return;
  const float* p = M + (size_t)row * EDIM;
  float4 a0 = *(const float4*)(p + lane * 8);
  float4 a1 = *(const float4*)(p + lane * 8 + 4);
  float4 w0 = *(const float4*)(fcw + lane * 8);
  float4 w1 = *(const float4*)(fcw + lane * 8 + 4);
  float dot = a0.x * w0.x + a0.y * w0.y + a0.z * w0.z + a0.w * w0.w +
              a1.x * w1.x + a1.y * w1.y + a1.z * w1.z + a1.w * w1.w;
  float ss = a0.x * a0.x + a0.y * a0.y + a0.z * a0.z + a0.w * a0.w +
             a1.x * a1.x + a1.y * a1.y + a1.z * a1.z + a1.w * a1.w;
  for (int s = 1; s < 64; s <<= 1) {
    dot += __shfl_xor(dot, s);
    ss += __shfl_xor(ss, s);
  }
  float inv = 1.0f / fmaxf(sqrtf(ss), 1e-12f);
  bf16x8 bv;
  bv[0] = (short)f2bf(a0.x * inv); bv[1] = (short)f2bf(a0.y * inv);
  bv[2] = (short)f2bf(a0.z * inv); bv[3] = (short)f2bf(a0.w * inv);
  bv[4] = (short)f2bf(a1.x * inv); bv[5] = (short)f2bf(a1.y * inv);
  bv[6] = (short)f2bf(a1.z * inv); bv[7] = (short)f2bf(a1.w * inv);
  *(bf16x8*)(Mbf + (size_t)row * EDIM + lane * 8) = bv;
  if (lane == 0) wout[row] = dot + fcb[0];
}

// ---------------- softmax: blocks 0..63 vw rows (196), 64..127 tw rows (64, masked) ----
__global__ void k_softmax(float* __restrict__ vwf, float* __restrict__ twf,
                          const int* __restrict__ tlen) {
  __shared__ float red[8];
  int tid = threadIdx.x;
  if (blockIdx.x < 64) {
    int b = blockIdx.x;
    float x = (tid < NV) ? vwf[b * NV + tid] : -1e30f;
    float m = x;
    for (int s = 1; s < 64; s <<= 1) m = fmaxf(m, __shfl_xor(m, s));
    if ((tid & 63) == 0) red[tid >> 6] = m;
    __syncthreads();
    m = fmaxf(fmaxf(red[0], red[1]), fmaxf(red[2], red[3]));
    float e = (tid < NV) ? expf(x - m) : 0.0f;
    float s = e;
    for (int st = 1; st < 64; st <<= 1) s += __shfl_xor(s, st);
    if ((tid & 63) == 0) red[4 + (tid >> 6)] = s;
    __syncthreads();
    s = red[4] + red[5] + red[6] + red[7];
    if (tid < NV) vwf[b * NV + tid] = e / s;
  } else {
    int b = blockIdx.x - 64;
    if (tid < 64) {
      int len = tlen[b];
      float x = twf[b * NT + tid];
      bool valid = tid < len;
      float xv = valid ? x : -1e30f;
      float m = xv;
      for (int s = 1; s < 64; s <<= 1) m = fmaxf(m, __shfl_xor(m, s));
      float e = valid ? expf(x - m) : 0.0f;
      float s = e;
      for (int st = 1; st < 64; st <<= 1) s += __shfl_xor(s, st);
      twf[b * NT + tid] = e / s;
    }
  }
}

// ---------------- MFMA sim kernel: one block per (b, q-pair), XCD-chunked -----------
// n&7 = XCD; each XCD owns 8 b's (its ve panels stay L2-resident), streams te once.
// dbuf + prefetch-before-compute; single barrier per kc.
__global__ __launch_bounds__(256, 2) void k_sim(
    const short* __restrict__ ve_bf, const short* __restrict__ te_bf,
    const float* __restrict__ vwf, const float* __restrict__ twf,
    float* __restrict__ out, int* __restrict__ gMT, int* __restrict__ gMV) {
  __shared__ short As[2][256 * 32];   // linear, 64B row stride
  __shared__ short Bs[2][128 * 32];
  __shared__ float colv[4][128];
  __shared__ int   coli[4][128];
  __shared__ float redp0[4], redp1[4];
  int n = blockIdx.x;
  int xcd = n & 7, idx = n >> 3;
  int b = xcd * 8 + (idx & 7);       // b-fastest within XCD chunk
  int qq = idx >> 3;                 // 0..31
  int tid = threadIdx.x;
  int w = tid >> 6, lane = tid & 63, lg = lane >> 4, li = lane & 15;
  const short* Abf = ve_bf + (size_t)b * NV * EDIM;
  const short* Bbf = te_bf + (size_t)qq * 128 * EDIM;
  int swz = li & 3;

  auto stage = [&](int bb, int kc) {
    int k0 = kc << 5;
    short* Ad = &As[bb][0];
    short* Bd = &Bs[bb][0];
#pragma unroll
    for (int uu = 0; uu < 2; ++uu) {   // B: 128 rows x 4 segs = 512 units
      int u0 = uu * 256 + w * 64;
      int u = u0 + lane;
      int row = u >> 2, seg = u & 3;
      int ss = seg ^ (row & 3);
      gload16(Bbf + (size_t)row * EDIM + k0 + ss * 8, Bd + u0 * 8);
    }
#pragma unroll
    for (int uu = 0; uu < 4; ++uu) {   // A: 784 valid units (rows clamped past 195)
      int u0 = uu * 256 + w * 64;
      if (u0 < NV * 4) {
        int u = u0 + lane;
        int row = u >> 2;
        if (row > NV - 1) row = NV - 1;
        int seg = u & 3;
        int ss = seg ^ (row & 3);
        gload16(Abf + (size_t)row * EDIM + k0 + ss * 8, Ad + u0 * 8);
      }
    }
  };

  f32x4 acc[4][8];
#pragma unroll
  for (int i = 0; i < 4; ++i)
#pragma unroll
    for (int j = 0; j < 8; ++j) acc[i][j] = (f32x4){0.f, 0.f, 0.f, 0.f};

  stage(0, 0);
  __syncthreads();   // buf0 ready
  int cur = 0;
  for (int kc = 0; kc < 16; ++kc) {
    if (kc < 15) stage(cur ^ 1, kc + 1);   // prefetch next kc under compute
    const short* Ab2 = &As[cur][0];
    const short* Bb2 = &Bs[cur][0];
    bf16x8 bfr[8];
#pragma unroll
    for (int j = 0; j < 8; ++j)
      bfr[j] = *(const bf16x8*)(Bb2 + (j * 16 + li) * 32 + (lg ^ swz) * 8);
#pragma unroll
    for (int i = 0; i < 4; ++i) {
      bf16x8 afr = *(const bf16x8*)(Ab2 + ((w * 4 + i) * 16 + li) * 32 + (lg ^ swz) * 8);
#pragma unroll
      for (int j = 0; j < 8; ++j)
        acc[i][j] = __builtin_amdgcn_mfma_f32_16x16x32_bf16(afr, bfr[j], acc[i][j], 0, 0, 0);
    }
    __syncthreads();   // drains prefetch; guards dbuf reuse
    cur ^= 1;
  }

  bool diag0 = (b == 2 * qq), diag1 = (b == 2 * qq + 1);
  // ---- row (over t) max+argmax per q; C layout: row=tile*16+lg*4+reg, col=j*16+li
  float ip0 = 0.f, ip1 = 0.f;
#pragma unroll
  for (int i = 0; i < 4; ++i) {
#pragma unroll
    for (int reg = 0; reg < 4; ++reg) {
      int v = (w * 4 + i) * 16 + lg * 4 + reg;
      float m = acc[i][0][reg];
      int ti = li;
#pragma unroll
      for (int j = 1; j < 4; ++j) {
        float vv = acc[i][j][reg];
        int t = j * 16 + li;
        if (vv > m) { m = vv; ti = t; }   // t ascending -> first-index kept
      }
      for (int d = 1; d < 16; d <<= 1) {  // within li-group (same row)
        float om = __shfl_xor(m, d);
        int oi = __shfl_xor(ti, d);
        if (om > m || (om == m && oi < ti)) { m = om; ti = oi; }
      }
      float m1 = acc[i][4][reg];
      int ti1 = li;
#pragma unroll
      for (int j = 5; j < 8; ++j) {
        float vv = acc[i][j][reg];
        int t = (j - 4) * 16 + li;
        if (vv > m1) { m1 = vv; ti1 = t; }
      }
      for (int d = 1; d < 16; d <<= 1) {
        float om = __shfl_xor(m1, d);
        int oi = __shfl_xor(ti1, d);
        if (om > m1 || (om == m1 && oi < ti1)) { m1 = om; ti1 = oi; }
      }
      if (li == 0 && v < NV) {
        float wv = vwf[b * NV + v];
        ip0 += wv * m;
        ip1 += wv * m1;
        if (diag0) gMT[b * NV + v] = b * NT + ti;
        if (diag1) gMT[b * NV + v] = b * NT + ti1;
      }
    }
  }
  for (int d = 1; d < 64; d <<= 1) {
    ip0 += __shfl_xor(ip0, d);
    ip1 += __shfl_xor(ip1, d);
  }
  if (lane == 0) { redp0[w] = ip0; redp1[w] = ip1; }
  // ---- col (over v) max+argmax for this wave's rows, all 128 cols
  float cm[8]; int cv[8];
#pragma unroll
  for (int j = 0; j < 8; ++j) { cm[j] = -3.0e38f; cv[j] = 0; }
#pragma unroll
  for (int i = 0; i < 4; ++i)
#pragma unroll
    for (int reg = 0; reg < 4; ++reg) {
      int v = (w * 4 + i) * 16 + lg * 4 + reg;
      bool ok = v < NV;
#pragma unroll
      for (int j = 0; j < 8; ++j) {
        float s = ok ? acc[i][j][reg] : -3.0e38f;
        if (s > cm[j]) { cm[j] = s; cv[j] = v; }  // v ascending per lane
      }
    }
#pragma unroll
  for (int j = 0; j < 8; ++j) {
    for (int d = 16; d < 64; d <<= 1) {   // mixes lg groups (same col)
      float om = __shfl_xor(cm[j], d);
      int ov = __shfl_xor(cv[j], d);
      if (om > cm[j] || (om == cm[j] && ov < cv[j])) { cm[j] = om; cv[j] = ov; }
    }
    if (lg == 0) { colv[w][j * 16 + li] = cm[j]; coli[w][j * 16 + li] = cv[j]; }
  }
  __syncthreads();
  if (tid < 128) {
    int t = tid;
    float m = colv[0][t];
    int bi = coli[0][t];
#pragma unroll
    for (int w2 = 1; w2 < 4; ++w2) {
      float om = colv[w2][t];
      int ov = coli[w2][t];
      if (om > m || (om == m && ov < bi)) { m = om; bi = ov; }
    }
    int q = 2 * qq + (t >> 6);
    int tt = t & 63;
    if (b == q) gMV[b * NT + tt] = b * NV + bi;
    float p = twf[q * NT + tt] * m;
    for (int d = 1; d < 64; d <<= 1) p += __shfl_xor(p, d);
    if ((tid & 63) == 0) out[4096 + b * 64 + q] = p;
  }
  if (tid == 0) {
    out[b * 64 + 2 * qq]     = redp0[0] + redp0[1] + redp0[2] + redp0[3];
    out[b * 64 + 2 * qq + 1] = redp1[0] + redp1[1] + redp1[2] + redp1[3];
  }
}

// ---------------- column stats from bf16 (sum, sumsq, weighted sum) ------
__global__ void k_stats(const short* __restrict__ ve_bf, const short* __restrict__ te_bf,
                        const int* __restrict__ gMT, const int* __restrict__ gMV,
                        const float* __restrict__ vwf, const float* __restrict__ twf,
                        float* __restrict__ statPart) {
  int stripe = blockIdx.x, chunk = blockIdx.y, m = blockIdx.z;
  int R = (m < 2) ? MROWS_T : MROWS_V;
  int nchunk = (R + 1023) >> 10;
  if (chunk >= nchunk) return;
  const short* M; const int* g; const float* w;
  if (m == 0)      { M = te_bf; g = 0;   w = twf; }
  else if (m == 1) { M = ve_bf; g = gMV; w = twf; }
  else if (m == 2) { M = ve_bf; g = 0;   w = vwf; }
  else             { M = te_bf; g = gMT; w = vwf; }
  int col = stripe * 64 + (threadIdx.x & 63);
  int rg = threadIdx.x >> 6;
  int r0 = chunk << 10;
  int r1 = min(r0 + 1024, R);
  float s = 0, ss = 0, sw = 0;
  for (int r = r0 + rg; r < r1; r += 4) {
    int row = g ? g[r] : r;
    float x = bf2f(M[(size_t)row * EDIM + col]);
    s += x; ss += x * x; sw += w[r] * x;
  }
  __shared__ float red[3][256];
  red[0][threadIdx.x] = s; red[1][threadIdx.x] = ss; red[2][threadIdx.x] = sw;
  __syncthreads();
  if (threadIdx.x < 64) {
    int c = threadIdx.x;
    float S  = red[0][c] + red[0][c + 64] + red[0][c + 128] + red[0][c + 192];
    float SS = red[1][c] + red[1][c + 64] + red[1][c + 128] + red[1][c + 192];
    float SW = red[2][c] + red[2][c + 64] + red[2][c + 128] + red[2][c + 192];
    size_t idx = ((size_t)(m * 13 + chunk) * 512 + stripe * 64 + c) * 3;
    statPart[idx] = S; statPart[idx + 1] = SS; statPart[idx + 2] = SW;
  }
}

__global__ void k_statfin(const float* __restrict__ statPart, float* __restrict__ stats) {
  int m = blockIdx.x, c = threadIdx.x;
  int R = (m < 2) ? MROWS_T : MROWS_V;
  int nchunk = (R + 1023) >> 10;
  float s = 0, ss = 0, sw = 0;
  for (int ch = 0; ch < nchunk; ch++) {
    size_t idx = ((size_t)(m * 13 + ch) * 512 + c) * 3;
    s += statPart[idx]; ss += statPart[idx + 1]; sw += statPart[idx + 2];
  }
  float mean = s / R;
  float var = (ss - s * mean) / (R - 1);  // ddof=1
  float rstd = 1.0f / sqrtf(var);
  stats[(m * 3 + 0) * 512 + c] = mean;
  stats[(m * 3 + 1) * 512 + c] = rstd;
  stats[(m * 3 + 2) * 512 + c] = sw;
}

// ------- transpose-materialize a-contiguous bf16 operands (w and gathers folded) ----
__global__ void k_materialize(const short* __restrict__ ve_bf, const short* __restrict__ te_bf,
                              const int* __restrict__ gMT, const int* __restrict__ gMV,
                              const float* __restrict__ vwf, const float* __restrict__ twf,
                              short* __restrict__ tTw, short* __restrict__ mvT,
                              short* __restrict__ vTw, short* __restrict__ mtT) {
  int z = blockIdx.z;
  int at = blockIdx.x, ct = blockIdx.y;
  int K = (z == 2 || z == 3) ? MROWS_V : MROWS_T;
  if (at * 64 >= K) return;
  const short* src; const int* g = 0; const float* w = 0; short* dst;
  if (z == 0)      { src = te_bf; w = twf; dst = tTw; }
  else if (z == 1) { src = ve_bf; g = gMV; dst = mvT; }
  else if (z == 2) { src = ve_bf; w = vwf; dst = vTw; }
  else             { src = te_bf; g = gMT; dst = mtT; }
  __shared__ float tile[64][67];
  int tid = threadIdx.x;
  for (int u = tid; u < 512; u += 256) {
    int a = u >> 3, cseg = (u & 7) << 3;
    int ga = at * 64 + a;
    int row = g ? g[ga] : ga;
    bf16x8 vv = *(const bf16x8*)(src + (size_t)row * EDIM + ct * 64 + cseg);
    float wa = w ? w[ga] : 1.0f;
#pragma unroll
    for (int j = 0; j < 8; j++) tile[a][cseg + j] = wa * bf2f(vv[j]);
  }
  __syncthreads();
  for (int u = tid; u < 512; u += 256) {
    int c = u >> 3, aseg = (u & 7) << 3;
    bf16x8 ov;
#pragma unroll
    for (int j = 0; j < 8; j++) ov[j] = (short)f2bf(tile[aseg + j][c]);
    *(bf16x8*)(dst + (size_t)(ct * 64 + c) * K + at * 64 + aseg) = ov;
  }
}

// ------- MFMA weighted GEMM: Spart[z][c][d] = sum_a AT[c][a]*BT[d][a] (split-K 4) ----
__global__ __launch_bounds__(256, 4) void k_wgemm2(
    const short* __restrict__ tTw, const short* __restrict__ mvT,
    const short* __restrict__ vTw, const short* __restrict__ mtT,
    float* __restrict__ Spart) {
  __shared__ short As[128 * 44];
  __shared__ short Bs[64 * 44];
  int c0 = blockIdx.x * 128, d0 = blockIdx.y * 64;
  int z = blockIdx.z;
  int which = z >> 2, slice = z & 3;
  const short* A = which ? vTw : tTw;
  const short* B = which ? mtT : mvT;
  int K = which ? MROWS_V : MROWS_T;
  int nch = (K >> 2) >> 5;             // 98 or 32 chunks of 32
  int a0 = slice * (K >> 2);
  int tid = threadIdx.x;
  int w = tid >> 6, lane = tid & 63, lg = lane >> 4, li = lane & 15;
  f32x4 acc[2][4];
#pragma unroll
  for (int i = 0; i < 2; ++i)
#pragma unroll
    for (int j = 0; j < 4; ++j) acc[i][j] = (f32x4){0.f, 0.f, 0.f, 0.f};
  for (int ch = 0; ch < nch; ++ch) {
    int ak = a0 + (ch << 5);
    __syncthreads();
#pragma unroll
    for (int uu = 0; uu < 2; ++uu) {
      int u = tid + uu * 256;
      int r = u >> 2, seg = (u & 3) << 3;
      *(bf16x8*)(As + r * 44 + seg) = *(const bf16x8*)(A + (size_t)(c0 + r) * K + ak + seg);
    }
    {
      int t = tid >> 2, seg = (tid & 3) << 3;
      *(bf16x8*)(Bs + t * 44 + seg) = *(const bf16x8*)(B + (size_t)(d0 + t) * K + ak + seg);
    }
    __syncthreads();
    bf16x8 bfr[4];
#pragma unroll
    for (int j = 0; j < 4; ++j)
      bfr[j] = *(const bf16x8*)(Bs + (j * 16 + li) * 44 + lg * 8);
#pragma unroll
    for (int i = 0; i < 2; ++i) {
      bf16x8 afr = *(const bf16x8*)(As + ((w * 2 + i) * 16 + li) * 44 + lg * 8);
#pragma unroll
      for (int j = 0; j < 4; ++j)
        acc[i][j] = __builtin_amdgcn_mfma_f32_16x16x32_bf16(afr, bfr[j], acc[i][j], 0, 0, 0);
    }
  }
  float* outp = Spart + (size_t)z * 512 * 512;
#pragma unroll
  for (int j = 0; j < 4; ++j) {
    int d = d0 + j * 16 + li;
#pragma unroll
    for (int i = 0; i < 2; ++i)
#pragma unroll
      for (int reg = 0; reg < 4; ++reg)
        outp[(size_t)(c0 + (w * 2 + i) * 16 + lg * 4 + reg) * 512 + d] = acc[i][j][reg];
  }
}

// ---------------- assemble c = (c1+c2)/2 from closed form; loss partials ----------
__global__ void k_assemble(const float* __restrict__ Spart, const float* __restrict__ stats,
                           float* __restrict__ lossPart) {
  int c = blockIdx.x, tid = threadIdx.x;
  float muT = stats[0 * 512 + c], rsT = stats[1 * 512 + c], swT = stats[2 * 512 + c];
  float muV = stats[6 * 512 + c], rsV = stats[7 * 512 + c], swV = stats[8 * 512 + c];
  const float W = 64.0f, invB = 1.0f / 64.0f;
  float on = 0, off = 0;
  for (int d = tid; d < 512; d += 256) {
    float s1 = 0, s2 = 0;
    for (int sl = 0; sl < 4; sl++) {
      s1 += Spart[((size_t)sl * 512 + c) * 512 + d];
      s2 += Spart[((size_t)(4 + sl) * 512 + c) * 512 + d];
    }
    float muMV = stats[3 * 512 + d], rsMV = stats[4 * 512 + d], swMV = stats[5 * 512 + d];
    float muMT = stats[9 * 512 + d], rsMT = stats[10 * 512 + d], swMT = stats[11 * 512 + d];
    float c1 = (s1 - muT * swMV - muMV * swT + muT * muMV * W) * rsT * rsMV * invB;
    float c2 = (s2 - muV * swMT - muMT * swV + muV * muMT * W) * rsV * rsMT * invB;
    float cc = 0.5f * (c1 + c2);
    if (d == c) { float dd = cc - 1.0f; on += dd * dd; }
    else off += cc * cc;
  }
  __shared__ float r1[4], r2[4];
  for (int s = 1; s < 64; s <<= 1) { on += __shfl_xor(on, s); off += __shfl_xor(off, s); }
  if ((tid & 63) == 0) { r1[tid >> 6] = on; r2[tid >> 6] = off; }
  __syncthreads();
  if (tid == 0) {
    lossPart[c * 2] = r1[0] + r1[1] + r1[2] + r1[3];
    lossPart[c * 2 + 1] = r2[0] + r2[1] + r2[2] + r2[3];
  }
}

__global__ void k_loss(const float* __restrict__ lossPart, float* __restrict__ out) {
  int tid = threadIdx.x;
  float on = 0, off = 0;
  for (int i = tid; i < 512; i += 256) { on += lossPart[2 * i]; off += lossPart[2 * i + 1]; }
  __shared__ float r1[4], r2[4];
  for (int s = 1; s < 64; s <<= 1) { on += __shfl_xor(on, s); off += __shfl_xor(off, s); }
  if ((tid & 63) == 0) { r1[tid >> 6] = on; r2[tid >> 6] = off; }
  __syncthreads();
  if (tid == 0)
    out[8192] = 0.1f * ((r1[0] + r1[1] + r1[2] + r1[3]) +
                        0.06f * (r2[0] + r2[1] + r2[2] + r2[3]));
}

extern "C" void kernel_launch(void* const* d_in, const int* in_sizes, int n_in,
                              void* d_out, int out_size, void* d_ws, size_t ws_size,
                              hipStream_t stream) {
  (void)in_sizes; (void)n_in; (void)out_size; (void)ws_size;
  const float* v_tok  = (const float*)d_in[1];
  const float* t_tok  = (const float*)d_in[3];
  const float* Wv_tok = (const float*)d_in[8];
  const float* Wt_tok = (const float*)d_in[10];
  const float* bv_tok = (const float*)d_in[9];
  const float* bt_tok = (const float*)d_in[11];
  const float* wv_fc  = (const float*)d_in[12];
  const float* bv_fc  = (const float*)d_in[13];
  const float* wt_fc  = (const float*)d_in[14];
  const float* bt_fc  = (const float*)d_in[15];
  const int*   tlen   = (const int*)d_in[16];
  float* out = (float*)d_out;

  char* wsb = (char*)d_ws;
  // --- R0 (27,131,904 B): phase 1 {v_tok_bf, t_tok_bf, WvT, WtT};
  //     after proj: {ve_bf, te_bf, Spart} (lifetime-disjoint, stream-ordered)
  short* v_tok_bf = (short*)wsb;                       // 9,633,792 sh
  short* t_tok_bf = v_tok_bf + (size_t)9633792;        // 3,145,728 sh
  short* WvT      = t_tok_bf + (size_t)3145728;        //   393,216 sh
  short* WtT      = WvT + (size_t)393216;              //   393,216 sh
  short* ve_bf    = (short*)wsb;                       // 6,422,528 sh (alias v_tok_bf)
  short* te_bf    = ve_bf + (size_t)6422528;           // 2,097,152 sh
  float* Spart    = (float*)(wsb + 17039360);          // 8*512*512 f (alias tail)
  // --- R1 (34,078,720 B): phase 1 {ve, te fp32}; after normfc: transposed operands
  float* ve  = (float*)(wsb + 27131904);               // 6,422,528 f
  float* te  = ve + (size_t)6422528;                   // 2,097,152 f
  short* tTw = (short*)(wsb + 27131904);               // 512*4096  (alias)
  short* mvT = tTw + (size_t)2097152;                  // 512*4096
  short* vTw = mvT + (size_t)2097152;                  // 512*12544
  short* mtT = vTw + (size_t)6422528;                  // 512*12544
  // --- R2 smalls
  float* vwf = (float*)(wsb + 61210624);               // 12544
  float* twf = vwf + 12544;                            // 4096
  int* gMT = (int*)(twf + 4096);                       // 12544
  int* gMV = gMT + 12544;                              // 4096
  float* statPart = (float*)(gMV + 4096);              // 4*13*512*3
  float* stats = statPart + 79872;                     // 12*512
  float* lossPart = stats + 6144;                      // 1024

  k_tobf16<<<4704, 256, 0, stream>>>(v_tok, v_tok_bf, 1204224);
  k_tobf16<<<1536, 256, 0, stream>>>(t_tok, t_tok_bf, 393216);
  k_transpose_bf<<<dim3(24, 16, 2), dim3(32, 8), 0, stream>>>(Wv_tok, Wt_tok, WvT, WtT);
  k_proj_mfma<<<dim3(8, 98), 256, 0, stream>>>(v_tok_bf, WvT, bv_tok, ve);
  k_proj_mfma<<<dim3(8, 32), 256, 0, stream>>>(t_tok_bf, WtT, bt_tok, te);
  k_normfc<<<3136, 256, 0, stream>>>(ve, wv_fc, bv_fc, vwf, ve_bf, 12544);
  k_normfc<<<1024, 256, 0, stream>>>(te, wt_fc, bt_fc, twf, te_bf, 4096);
  k_softmax<<<128, 256, 0, stream>>>(vwf, twf, tlen);
  k_sim<<<2048, 256, 0, stream>>>(ve_bf, te_bf, vwf, twf, out, gMT, gMV);
  k_stats<<<dim3(8, 13, 4), 256, 0, stream>>>(ve_bf, te_bf, gMT, gMV, vwf, twf, statPart);
  k_statfin<<<4, 512, 0, stream>>>(statPart, stats);
  k_materialize<<<dim3(196, 8, 4), 256, 0, stream>>>(ve_bf, te_bf, gMT, gMV, vwf, twf,
                                                     tTw, mvT, vTw, mtT);
  k_wgemm2<<<dim3(4, 8, 8), 256, 0, stream>>>(tTw, mvT, vTw, mtT, Spart);
  k_assemble<<<512, 256, 0, stream>>>(Spart, stats, lossPart);
  k_loss<<<1, 256, 0, stream>>>(lossPart, out);
}